// Round 4
// baseline (430.984 us; speedup 1.0000x reference)
//
#include <hip/hip_runtime.h>
#include <hip/hip_fp16.h>
#include <math.h>

#define NN 50000
#define NE 800000

static inline int ceil_div_h(int a, int b) { return (a + b - 1) / b; }

typedef _Float16 half8 __attribute__((ext_vector_type(8)));
typedef float f32x4 __attribute__((ext_vector_type(4)));

// ---------------- prep: all weight transposes + fp16 convert + cursor zero ----------------
// Wt layout: [wt1 128x256 | wt2 128x128 | wtg1 256x128 | wtg2 128x256 | wtg3 64x64]
__global__ __launch_bounds__(256)
void prep_kernel(const float* __restrict__ w1, const float* __restrict__ w2,
                 const float* __restrict__ g1w, const float* __restrict__ g2w,
                 const float* __restrict__ g3w, __half* __restrict__ wt,
                 int* __restrict__ cursor) {
  int idx = blockIdx.x * 256 + threadIdx.x;
  if (idx < NN) cursor[idx] = 0;
  const float* W; int K, N, li;
  if (idx < 32768)        { W = w1;  K = 256; N = 128; li = idx; }
  else if (idx < 49152)   { W = w2;  K = 128; N = 128; li = idx - 32768; }
  else if (idx < 81920)   { W = g1w; K = 128; N = 256; li = idx - 49152; }
  else if (idx < 114688)  { W = g2w; K = 256; N = 128; li = idx - 81920; }
  else if (idx < 118784)  { W = g3w; K = 64;  N = 64;  li = idx - 114688; }
  else return;
  int n = li / K, k = li - n * K;
  wt[idx] = __float2half_rn(W[(size_t)k * N + n]);
}

// ---------------- fused MLP + GAT1 linear: x -> h1 -> h2 -> xh1 (+ scores) ----------------
// One block = 64 rows. h1/h2 live only in LDS. Phase 3 overlays its 256-row weight
// staging onto [Bs12|h1s] (h1s dead) -> 50.2 KB LDS total -> 3 blocks/CU.
__global__ __launch_bounds__(256)
void mlp_gat1_fused(const float* __restrict__ x,
                    const __half* __restrict__ wt1,   // [128][256]
                    const float* __restrict__ b1,
                    const __half* __restrict__ wt2,   // [128][128]
                    const float* __restrict__ b2,
                    const __half* __restrict__ wtg1,  // [256][128]
                    const float* __restrict__ a_src, const float* __restrict__ a_dst,
                    __half* __restrict__ xh1,
                    float* __restrict__ s_src, float* __restrict__ s_dst) {
  constexpr int SA = 40;    // staging stride in halves (80 B, 16B-aligned)
  constexpr int SH = 136;   // h-tile stride in halves (2-way bank alias = free)
  // layout (halves): As 2560 | Bs12 5120 | h1s 8704 | h2s 8704  = 25088 (50.2 KB)
  // phase 3 weight staging Bs3 = Bs12 start, 10240 halves (overlaps h1s).
  __shared__ __align__(16) _Float16 smem[25088];
  _Float16* As   = smem;
  _Float16* Bs12 = smem + 2560;
  _Float16* h1s  = smem + 7680;
  _Float16* h2s  = smem + 16384;
  _Float16* Bs3  = Bs12;
  const int tid = threadIdx.x;
  const int bm = blockIdx.x * 64;
  const int wave = tid >> 6, lane = tid & 63;
  const int l16 = lane & 15, quad = lane >> 4;
  const int wm = (wave & 1) * 32;     // phase 1/2: 2x2 wave layout, tile 32x64
  const int wn = (wave >> 1) * 64;

  // ---- phase 1: h1 = relu(x @ w1 + b1), [64x128], K=256 ----
  {
    f32x4 acc[2][4] = {};
    for (int k0 = 0; k0 < 256; k0 += 32) {
      #pragma unroll
      for (int i = 0; i < 2; ++i) {
        int idx = tid + i * 256;
        int m = idx >> 3, q = idx & 7;
        int gm = bm + m;
        float4 v = make_float4(0.f, 0.f, 0.f, 0.f);
        if (gm < NN) v = *(const float4*)&x[(size_t)gm * 256 + k0 + q * 4];
        union { __half2 h2[2]; float2 f2; } u;
        u.h2[0] = __floats2half2_rn(v.x, v.y);
        u.h2[1] = __floats2half2_rn(v.z, v.w);
        *(float2*)&As[m * SA + q * 4] = u.f2;
      }
      #pragma unroll
      for (int i = 0; i < 2; ++i) {
        int idx = tid + i * 256;
        int n = idx >> 2, kq = (idx & 3) * 8;
        *(float4*)&Bs12[n * SA + kq] = *(const float4*)&wt1[(size_t)n * 256 + k0 + kq];
      }
      __syncthreads();
      half8 af[2], bf[4];
      #pragma unroll
      for (int mi = 0; mi < 2; ++mi)
        af[mi] = *(const half8*)&As[(wm + mi * 16 + l16) * SA + quad * 8];
      #pragma unroll
      for (int ni = 0; ni < 4; ++ni)
        bf[ni] = *(const half8*)&Bs12[(wn + ni * 16 + l16) * SA + quad * 8];
      #pragma unroll
      for (int mi = 0; mi < 2; ++mi)
        #pragma unroll
        for (int ni = 0; ni < 4; ++ni)
          acc[mi][ni] = __builtin_amdgcn_mfma_f32_16x16x32_f16(af[mi], bf[ni], acc[mi][ni], 0, 0, 0);
      __syncthreads();
    }
    #pragma unroll
    for (int mi = 0; mi < 2; ++mi)
      #pragma unroll
      for (int r = 0; r < 4; ++r) {
        int row = wm + mi * 16 + quad * 4 + r;
        #pragma unroll
        for (int ni = 0; ni < 4; ++ni) {
          int col = wn + ni * 16 + l16;
          float v = acc[mi][ni][r] + b1[col];
          v = fmaxf(v, 0.f);
          h1s[row * SH + col] = (_Float16)v;
        }
      }
  }
  __syncthreads();

  // ---- phase 2: h2 = relu(h1 @ w2 + b2), [64x128], K=128, A from LDS ----
  {
    f32x4 acc[2][4] = {};
    for (int k0 = 0; k0 < 128; k0 += 32) {
      #pragma unroll
      for (int i = 0; i < 2; ++i) {
        int idx = tid + i * 256;
        int n = idx >> 2, kq = (idx & 3) * 8;
        *(float4*)&Bs12[n * SA + kq] = *(const float4*)&wt2[(size_t)n * 128 + k0 + kq];
      }
      __syncthreads();
      half8 af[2], bf[4];
      #pragma unroll
      for (int mi = 0; mi < 2; ++mi)
        af[mi] = *(const half8*)&h1s[(wm + mi * 16 + l16) * SH + k0 + quad * 8];
      #pragma unroll
      for (int ni = 0; ni < 4; ++ni)
        bf[ni] = *(const half8*)&Bs12[(wn + ni * 16 + l16) * SA + quad * 8];
      #pragma unroll
      for (int mi = 0; mi < 2; ++mi)
        #pragma unroll
        for (int ni = 0; ni < 4; ++ni)
          acc[mi][ni] = __builtin_amdgcn_mfma_f32_16x16x32_f16(af[mi], bf[ni], acc[mi][ni], 0, 0, 0);
      __syncthreads();
    }
    #pragma unroll
    for (int mi = 0; mi < 2; ++mi)
      #pragma unroll
      for (int r = 0; r < 4; ++r) {
        int row = wm + mi * 16 + quad * 4 + r;
        #pragma unroll
        for (int ni = 0; ni < 4; ++ni) {
          int col = wn + ni * 16 + l16;
          float v = acc[mi][ni][r] + b2[col];
          v = fmaxf(v, 0.f);
          h2s[row * SH + col] = (_Float16)v;
        }
      }
  }
  __syncthreads();

  // ---- phase 3: xh1 = h2 @ wg1, [64x256], K=128; wave = head; Bs3 overlays h1s ----
  {
    f32x4 acc[4][4] = {};
    const int wn3 = wave * 64;
    for (int k0 = 0; k0 < 128; k0 += 32) {
      #pragma unroll
      for (int i = 0; i < 4; ++i) {
        int idx = tid + i * 256;
        int n = idx >> 2, kq = (idx & 3) * 8;
        *(float4*)&Bs3[n * SA + kq] = *(const float4*)&wtg1[(size_t)n * 128 + k0 + kq];
      }
      __syncthreads();
      half8 af[4], bf[4];
      #pragma unroll
      for (int mi = 0; mi < 4; ++mi)
        af[mi] = *(const half8*)&h2s[(mi * 16 + l16) * SH + k0 + quad * 8];
      #pragma unroll
      for (int ni = 0; ni < 4; ++ni)
        bf[ni] = *(const half8*)&Bs3[(wn3 + ni * 16 + l16) * SA + quad * 8];
      #pragma unroll
      for (int mi = 0; mi < 4; ++mi)
        #pragma unroll
        for (int ni = 0; ni < 4; ++ni)
          acc[mi][ni] = __builtin_amdgcn_mfma_f32_16x16x32_f16(af[mi], bf[ni], acc[mi][ni], 0, 0, 0);
      __syncthreads();
    }
    // epilogue: store xh1 fp16 + fused scores (head h = wave)
    float asv[4], adv[4];
    #pragma unroll
    for (int ni = 0; ni < 4; ++ni) {
      int d = ni * 16 + l16;
      asv[ni] = a_src[wave * 64 + d];
      adv[ni] = a_dst[wave * 64 + d];
    }
    #pragma unroll
    for (int mi = 0; mi < 4; ++mi) {
      #pragma unroll
      for (int r = 0; r < 4; ++r) {
        int gm = bm + mi * 16 + quad * 4 + r;
        float ss = 0.f, sd = 0.f;
        #pragma unroll
        for (int ni = 0; ni < 4; ++ni) {
          float v = acc[mi][ni][r];
          ss = fmaf(v, asv[ni], ss);
          sd = fmaf(v, adv[ni], sd);
          if (gm < NN) xh1[(size_t)gm * 256 + wn3 + ni * 16 + l16] = __float2half_rn(v);
        }
        #pragma unroll
        for (int off = 1; off < 16; off <<= 1) {
          ss += __shfl_xor(ss, off, 64);
          sd += __shfl_xor(sd, off, 64);
        }
        if (l16 == 0 && gm < NN) {
          s_src[gm * 4 + wave] = ss;
          s_dst[gm * 4 + wave] = sd;
        }
      }
    }
  }
}

// ---------------- MFMA GEMM (GAT2/GAT3): C = act(A @ B + bias), optional fused scores ----
template<int BM, int TN, int WR, int WC, int ACT, int OUTH, int AF32, int HS>
__global__ __launch_bounds__(256)
void mfma_gemm(const void* __restrict__ Av, const __half* __restrict__ Bt,
               const float* __restrict__ bias, void* __restrict__ Cv,
               const float* __restrict__ a_src, const float* __restrict__ a_dst,
               float* __restrict__ s_src, float* __restrict__ s_dst,
               int M, int N, int K) {
  constexpr int FM = BM / WR / 16;
  constexpr int FN = TN / WC / 16;
  constexpr int SA = 40;
  __shared__ __align__(16) _Float16 As[BM * SA];
  __shared__ __align__(16) _Float16 Bs[TN * SA];
  const int tid = threadIdx.x;
  const int bm = blockIdx.y * BM, bn = blockIdx.x * TN;
  const int wave = tid >> 6, lane = tid & 63;
  const int wm = (wave % WR) * (BM / WR);
  const int wn = (wave / WR) * (TN / WC);
  const int l16 = lane & 15, quad = lane >> 4;

  f32x4 acc[FM][FN] = {};

  for (int k0 = 0; k0 < K; k0 += 32) {
    if (AF32) {
      const float* A = (const float*)Av;
      #pragma unroll
      for (int i = 0; i < (BM * 8) / 256; ++i) {
        int idx = tid + i * 256;
        int m = idx >> 3, q = idx & 7;
        int gm = bm + m;
        float4 v = make_float4(0.f, 0.f, 0.f, 0.f);
        if (gm < M) v = *(const float4*)&A[(size_t)gm * K + k0 + q * 4];
        union { __half2 h2[2]; float2 f2; } u;
        u.h2[0] = __floats2half2_rn(v.x, v.y);
        u.h2[1] = __floats2half2_rn(v.z, v.w);
        *(float2*)&As[m * SA + q * 4] = u.f2;
      }
    } else {
      const __half* A = (const __half*)Av;
      #pragma unroll
      for (int i = 0; i < (BM * 4) / 256; ++i) {
        int idx = tid + i * 256;
        int m = idx >> 2, q = (idx & 3) * 8;
        int gm = bm + m;
        float4 raw = make_float4(0.f, 0.f, 0.f, 0.f);
        if (gm < M) raw = *(const float4*)&A[(size_t)gm * K + k0 + q];
        *(float4*)&As[m * SA + q] = raw;
      }
    }
    #pragma unroll
    for (int i = 0; i < (TN * 4) / 256; ++i) {
      int idx = tid + i * 256;
      int n = idx >> 2, kq = (idx & 3) * 8;
      float4 raw = *(const float4*)&Bt[(size_t)(bn + n) * K + k0 + kq];
      *(float4*)&Bs[n * SA + kq] = raw;
    }
    __syncthreads();
    half8 af[FM], bf[FN];
    #pragma unroll
    for (int mi = 0; mi < FM; ++mi)
      af[mi] = *(const half8*)&As[(wm + mi * 16 + l16) * SA + quad * 8];
    #pragma unroll
    for (int ni = 0; ni < FN; ++ni)
      bf[ni] = *(const half8*)&Bs[(wn + ni * 16 + l16) * SA + quad * 8];
    #pragma unroll
    for (int mi = 0; mi < FM; ++mi)
      #pragma unroll
      for (int ni = 0; ni < FN; ++ni)
        acc[mi][ni] = __builtin_amdgcn_mfma_f32_16x16x32_f16(af[mi], bf[ni], acc[mi][ni], 0, 0, 0);
    __syncthreads();
  }

  #pragma unroll
  for (int mi = 0; mi < FM; ++mi) {
    #pragma unroll
    for (int r = 0; r < 4; ++r) {
      int gm = bm + wm + mi * 16 + quad * 4 + r;
      if (gm >= M) continue;
      #pragma unroll
      for (int ni = 0; ni < FN; ++ni) {
        int gn = bn + wn + ni * 16 + l16;
        float v = acc[mi][ni][r];
        if (bias) v += bias[gn];
        if (ACT == 1) v = fmaxf(v, 0.f);
        if (OUTH) ((__half*)Cv)[(size_t)gm * N + gn] = __float2half_rn(v);
        else      ((float*)Cv)[(size_t)gm * N + gn] = v;
      }
    }
  }

  if (HS > 0) {
    const int h = (bn + wn) >> 6;
    float asv[FN], adv[FN];
    #pragma unroll
    for (int ni = 0; ni < FN; ++ni) {
      int d = ni * 16 + l16;
      asv[ni] = a_src[h * 64 + d];
      adv[ni] = a_dst[h * 64 + d];
    }
    #pragma unroll
    for (int mi = 0; mi < FM; ++mi) {
      #pragma unroll
      for (int r = 0; r < 4; ++r) {
        float ss = 0.f, sd = 0.f;
        #pragma unroll
        for (int ni = 0; ni < FN; ++ni) {
          float v = acc[mi][ni][r];
          ss = fmaf(v, asv[ni], ss);
          sd = fmaf(v, adv[ni], sd);
        }
        #pragma unroll
        for (int off = 1; off < 16; off <<= 1) {
          ss += __shfl_xor(ss, off, 64);
          sd += __shfl_xor(sd, off, 64);
        }
        int gm = bm + wm + mi * 16 + quad * 4 + r;
        if (l16 == 0 && gm < M) {
          s_src[gm * HS + h] = ss;
          s_dst[gm * HS + h] = sd;
        }
      }
    }
  }
}

// ---------------- CSR build over the NE real edges ----------------

__global__ __launch_bounds__(256)
void hist_kernel(const int* __restrict__ ei, int* __restrict__ cnt) {
  int e = blockIdx.x * blockDim.x + threadIdx.x;
  if (e >= NE) return;
  atomicAdd(&cnt[ei[NE + e]], 1);
}

__global__ __launch_bounds__(256)
void scan1_kernel(const int* __restrict__ in, int* __restrict__ out,
                  int* __restrict__ bsum, int n) {
  __shared__ int tmp[256];
  int t = threadIdx.x;
  int i = blockIdx.x * 256 + t;
  int v = (i < n) ? in[i] : 0;
  tmp[t] = v;
  __syncthreads();
  for (int off = 1; off < 256; off <<= 1) {
    int u = (t >= off) ? tmp[t - off] : 0;
    __syncthreads();
    tmp[t] += u;
    __syncthreads();
  }
  if (i <= n) out[i] = tmp[t] - v;
  if (t == 255) bsum[blockIdx.x] = tmp[255];
}

// scan2 merged in: every block redundantly scans the (<=256) block sums in LDS,
// then applies its exclusive prefix. Saves one kernel launch.
__global__ __launch_bounds__(256)
void scan3_kernel(int* __restrict__ out, const int* __restrict__ bsum,
                  int* __restrict__ cursor, int n, int nb) {
  __shared__ int tmp[256];
  int t = threadIdx.x;
  int bv = (t < nb) ? bsum[t] : 0;
  tmp[t] = bv;
  __syncthreads();
  for (int off = 1; off < 256; off <<= 1) {
    int u = (t >= off) ? tmp[t - off] : 0;
    __syncthreads();
    tmp[t] += u;
    __syncthreads();
  }
  int add = tmp[blockIdx.x] - ((blockIdx.x < nb) ? bsum[blockIdx.x] : 0);
  int i = blockIdx.x * 256 + t;
  if (i > n) return;
  int v = out[i] + add;
  out[i] = v;
  if (i < n) cursor[i] = v;
}

__global__ __launch_bounds__(256)
void scatter_kernel(const int* __restrict__ ei, int* __restrict__ cursor,
                    int* __restrict__ srcs) {
  int e = blockIdx.x * blockDim.x + threadIdx.x;
  if (e >= NE) return;
  int s = ei[e], d = ei[NE + e];
  int pos = atomicAdd(&cursor[d], 1);
  srcs[pos] = s;
}

// ---------------- GAT1 aggregate (H=4): one wave per node, LDS-staged weights ----
// At the request-bandwidth roofline (~7 TB/s incl. cache hits) -- round-0 config.
__global__ __launch_bounds__(256)
void gat_aggregate4(const int* __restrict__ rowptr, const int* __restrict__ srcs,
                    const float* __restrict__ ssrc, const float* __restrict__ sdst,
                    const __half* __restrict__ xh, const float* __restrict__ bias,
                    __half* __restrict__ out) {
  constexpr int H = 4, HD = 256;
  __shared__ float wbuf[4][64 * H];
  __shared__ int sbuf[4][64];
  const int wslot = threadIdx.x >> 6;
  const int wid = (blockIdx.x * blockDim.x + threadIdx.x) >> 6;
  const int lane = threadIdx.x & 63;
  if (wid >= NN) return;
  const int n = wid;
  const int start = rowptr[n];
  const int end = rowptr[n + 1];
  const int h = lane >> 4;

  float sdv[H];
  #pragma unroll
  for (int hh = 0; hh < H; ++hh) sdv[hh] = sdst[n * H + hh];

  float z;
  float acc[H];
  {
    float wself[H];
    #pragma unroll
    for (int hh = 0; hh < H; ++hh) {
      float e = ssrc[n * H + hh] + sdv[hh];
      e = e >= 0.f ? e : 0.2f * e;
      wself[hh] = __expf(e);
    }
    float ws = wself[h];
    z = ws;
    const __half* xr = xh + (size_t)n * HD + lane * H;
    float2 raw = *(const float2*)xr;
    __half2 p0 = *(__half2*)&raw.x;
    __half2 p1 = *(__half2*)&raw.y;
    float2 f0 = __half22float2(p0), f1 = __half22float2(p1);
    acc[0] = ws * f0.x; acc[1] = ws * f0.y; acc[2] = ws * f1.x; acc[3] = ws * f1.y;
  }

  for (int base = start; base < end; base += 64) {
    int cnt = end - base;
    if (cnt > 64) cnt = 64;
    if (lane < cnt) {
      int s = srcs[base + lane];
      sbuf[wslot][lane] = s;
      float4 t = *(const float4*)&ssrc[s * 4];
      float ev[H] = {t.x, t.y, t.z, t.w};
      #pragma unroll
      for (int hh = 0; hh < H; ++hh) {
        float e = ev[hh] + sdv[hh];
        e = e >= 0.f ? e : 0.2f * e;
        wbuf[wslot][lane * H + hh] = __expf(e);
      }
    }
    #pragma unroll 4
    for (int j = 0; j < cnt; ++j) {
      int s = sbuf[wslot][j];
      float w = wbuf[wslot][j * H + h];
      z += w;
      const __half* xr = xh + (size_t)s * HD + lane * H;
      float2 raw = *(const float2*)xr;
      __half2 p0 = *(__half2*)&raw.x;
      __half2 p1 = *(__half2*)&raw.y;
      float2 f0 = __half22float2(p0), f1 = __half22float2(p1);
      acc[0] = fmaf(w, f0.x, acc[0]); acc[1] = fmaf(w, f0.y, acc[1]);
      acc[2] = fmaf(w, f1.x, acc[2]); acc[3] = fmaf(w, f1.y, acc[3]);
    }
  }
  const float inv = 1.f / z;

  float v[4];
  #pragma unroll
  for (int i = 0; i < 4; ++i) {
    v[i] = acc[i] * inv + bias[lane * 4 + i];
    v[i] = v[i] > 0.f ? v[i] : expm1f(v[i]);
  }
  union { __half2 h2[2]; float2 f2; } u;
  u.h2[0] = __floats2half2_rn(v[0], v[1]);
  u.h2[1] = __floats2half2_rn(v[2], v[3]);
  *(float2*)&out[(size_t)n * 256 + lane * 4] = u.f2;
}

// ---------------- GAT2/GAT3 aggregate: sub-wave decomposition ----------------
// These layers are edge-issue-bound, not bytes-bound (rows are 256 B / 128 B).
// Split the wave into NSUB subgroups, one node each; 8 B/lane covers the full row.
// Per wave-iteration NSUB edges retire at ~the cost one edge had before.
// MODE 1: H=2, mean-over-heads + bias + ELU -> fp16 [NN][64]
// MODE 2: H=1, + bias -> fp32 [NN][64]
template<int H, int MODE>
__global__ __launch_bounds__(256)
void gat_aggregate_sub(const int* __restrict__ rowptr, const int* __restrict__ srcs,
                       const float* __restrict__ ssrc, const float* __restrict__ sdst,
                       const __half* __restrict__ xh, const float* __restrict__ bias,
                       void* __restrict__ outv) {
  constexpr int HD   = H * 64;      // halves per feature row: 128 / 64
  constexpr int GL   = HD / 4;      // lanes per subgroup (4 halves = 8 B each): 32 / 16
  constexpr int NSUB = 64 / GL;     // nodes per wave: 2 / 4
  const int wid  = (blockIdx.x * blockDim.x + threadIdx.x) >> 6;
  const int lane = threadIdx.x & 63;
  const int sg = lane / GL;
  const int p  = lane - sg * GL;    // lane's 8 B slot within the row
  const int n  = wid * NSUB + sg;
  const int hp = (p * 4) >> 6;      // head owning this lane's features (0 for H=1)
  const bool alive = (n < NN);

  int start = 0, end = 0;
  float sdv = 0.f;
  if (alive) {
    start = rowptr[n];
    end = rowptr[n + 1];
    sdv = sdst[n * H + hp];
  }

  float z = 0.f;
  float a0 = 0.f, a1 = 0.f, a2 = 0.f, a3 = 0.f;

  if (alive) {
    // self loop
    float e = ssrc[n * H + hp] + sdv;
    e = e >= 0.f ? e : 0.2f * e;
    float w = __expf(e);
    z = w;
    float2 raw = *(const float2*)(xh + (size_t)n * HD + p * 4);
    __half2 p0 = *(__half2*)&raw.x, p1 = *(__half2*)&raw.y;
    float2 f0 = __half22float2(p0), f1 = __half22float2(p1);
    a0 = w * f0.x; a1 = w * f0.y; a2 = w * f1.x; a3 = w * f1.y;
  }

  // divergent per-subgroup edge loop (exec-masked; NSUB independent streams/wave)
  for (int j = start; j < end; ++j) {
    int s = srcs[j];                          // broadcast within subgroup
    float e = ssrc[s * H + hp] + sdv;         // broadcast (1-2 lines)
    e = e >= 0.f ? e : 0.2f * e;
    float w = __expf(e);
    z += w;
    float2 raw = *(const float2*)(xh + (size_t)s * HD + p * 4);
    __half2 p0 = *(__half2*)&raw.x, p1 = *(__half2*)&raw.y;
    float2 f0 = __half22float2(p0), f1 = __half22float2(p1);
    a0 = fmaf(w, f0.x, a0); a1 = fmaf(w, f0.y, a1);
    a2 = fmaf(w, f1.x, a2); a3 = fmaf(w, f1.y, a3);
  }

  const float inv = 1.f / z;

  if (MODE == 1) {
    // normalized per-head values; pair feature d of head0 (p<16) with head1 (p+16)
    float v0 = a0 * inv, v1 = a1 * inv, v2 = a2 * inv, v3 = a3 * inv;
    float o0 = __shfl_xor(v0, 16, 64);
    float o1 = __shfl_xor(v1, 16, 64);
    float o2 = __shfl_xor(v2, 16, 64);
    float o3 = __shfl_xor(v3, 16, 64);
    if (alive && hp == 0) {
      float m0 = (v0 + o0) * 0.5f + bias[p * 4 + 0];
      float m1 = (v1 + o1) * 0.5f + bias[p * 4 + 1];
      float m2 = (v2 + o2) * 0.5f + bias[p * 4 + 2];
      float m3 = (v3 + o3) * 0.5f + bias[p * 4 + 3];
      m0 = m0 > 0.f ? m0 : expm1f(m0);
      m1 = m1 > 0.f ? m1 : expm1f(m1);
      m2 = m2 > 0.f ? m2 : expm1f(m2);
      m3 = m3 > 0.f ? m3 : expm1f(m3);
      __half* out = (__half*)outv;
      union { __half2 h2[2]; float2 f2; } u;
      u.h2[0] = __floats2half2_rn(m0, m1);
      u.h2[1] = __floats2half2_rn(m2, m3);
      *(float2*)&out[(size_t)n * 64 + p * 4] = u.f2;
    }
  } else {
    if (alive) {
      float* out = (float*)outv;
      float4 o = make_float4(a0 * inv + bias[p * 4 + 0],
                             a1 * inv + bias[p * 4 + 1],
                             a2 * inv + bias[p * 4 + 2],
                             a3 * inv + bias[p * 4 + 3]);
      *(float4*)&out[(size_t)n * 64 + p * 4] = o;
    }
  }
}

// ---------------- orchestration ----------------

extern "C" void kernel_launch(void* const* d_in, const int* in_sizes, int n_in,
                              void* d_out, int out_size, void* d_ws, size_t ws_size,
                              hipStream_t stream) {
  const float* x    = (const float*)d_in[0];
  const int*   ei   = (const int*)d_in[1];
  const float* w1   = (const float*)d_in[2];
  const float* b1   = (const float*)d_in[3];
  const float* w2   = (const float*)d_in[4];
  const float* b2   = (const float*)d_in[5];
  const float* g1w  = (const float*)d_in[6];
  const float* g1as = (const float*)d_in[7];
  const float* g1ad = (const float*)d_in[8];
  const float* g1b  = (const float*)d_in[9];
  const float* g2w  = (const float*)d_in[10];
  const float* g2as = (const float*)d_in[11];
  const float* g2ad = (const float*)d_in[12];
  const float* g2b  = (const float*)d_in[13];
  const float* g3w  = (const float*)d_in[14];
  const float* g3as = (const float*)d_in[15];
  const float* g3ad = (const float*)d_in[16];
  const float* g3b  = (const float*)d_in[17];
  float* out = (float*)d_out;

  float* ws   = (float*)d_ws;
  float* bufA = ws;
  float* bufB = bufA + (size_t)NN * 256;
  float* bufC = bufB + (size_t)NN * 256;
  float* ssrc = bufC + (size_t)NN * 256;     // NN*4
  float* sdst = ssrc + (size_t)NN * 4;       // NN*4
  int* rowptr = (int*)(sdst + (size_t)NN * 4);  // NN+1
  int* cursor = rowptr + (NN + 1);              // NN
  int* bsum   = cursor + NN;                    // 256
  int* srcs   = bsum + 256;                     // NE
  __half* wt   = (__half*)(srcs + NE);          // 118784 halves
  __half* wt1  = wt;                            // 128x256
  __half* wt2  = wt + 32768;                    // 128x128
  __half* wtg1 = wt + 49152;                    // 256x128
  __half* wtg2 = wt + 81920;                    // 128x256
  __half* wtg3 = wt + 114688;                   // 64x64

  __half* xh1 = (__half*)bufC;   // NN*256
  __half* a1  = (__half*)bufA;   // NN*256
  __half* xh2 = (__half*)bufB;   // NN*128
  __half* a2  = (__half*)bufC;   // NN*64  (xh1 dead)
  __half* xh3 = (__half*)bufB;   // NN*64  (xh2 dead)

  const int TB = 256;
  const int grid_m = ceil_div_h(NN, 64);        // 782
  const int egrid = ceil_div_h(NE, TB);
  const int sgrid = ceil_div_h(NN + 1, TB);
  const int wgrid = ceil_div_h(NN, 4);

  // ---- prep: weight convert + cursor zero ----
  prep_kernel<<<ceil_div_h(118784, TB), TB, 0, stream>>>(w1, w2, g1w, g2w, g3w, wt, cursor);

  // ---- CSR build (separate kernels: full oversubscription for hist/scatter) ----
  hist_kernel<<<egrid, TB, 0, stream>>>(ei, cursor);
  scan1_kernel<<<sgrid, TB, 0, stream>>>(cursor, rowptr, bsum, NN);
  scan3_kernel<<<sgrid, TB, 0, stream>>>(rowptr, bsum, cursor, NN, sgrid);
  scatter_kernel<<<egrid, TB, 0, stream>>>(ei, cursor, srcs);

  // ---- fused MLP + GAT1 linear: x -> h1 -> h2 -> xh1 (+scores) ----
  mlp_gat1_fused<<<grid_m, TB, 0, stream>>>(x, wt1, b1, wt2, b2, wtg1,
                                            g1as, g1ad, xh1, ssrc, sdst);
  gat_aggregate4<<<wgrid, TB, 0, stream>>>(rowptr, srcs, ssrc, sdst, xh1, g1b, a1);

  // ---- GAT2: 256 -> 2x64, mean, ELU; scores fused ----
  mfma_gemm<64, 128, 2, 2, 0, 1, 0, 2><<<dim3(1, grid_m), TB, 0, stream>>>(
      a1, wtg2, nullptr, xh2, g2as, g2ad, ssrc, sdst, NN, 128, 256);
  gat_aggregate_sub<2, 1><<<ceil_div_h(NN, 8), TB, 0, stream>>>(
      rowptr, srcs, ssrc, sdst, xh2, g2b, a2);

  // ---- GAT3: 64 -> 1x64, identity mean, no ELU; scores fused ----
  mfma_gemm<64, 64, 4, 1, 0, 1, 0, 1><<<dim3(1, grid_m), TB, 0, stream>>>(
      a2, wtg3, nullptr, xh3, g3as, g3ad, ssrc, sdst, NN, 64, 64);
  gat_aggregate_sub<1, 2><<<ceil_div_h(NN, 16), TB, 0, stream>>>(
      rowptr, srcs, ssrc, sdst, xh3, g3b, out);
}

// Round 5
// 396.465 us; speedup vs baseline: 1.0871x; 1.0871x over previous
//
#include <hip/hip_runtime.h>
#include <hip/hip_fp16.h>
#include <math.h>

#define NN 50000
#define NE 800000

static inline int ceil_div_h(int a, int b) { return (a + b - 1) / b; }

typedef _Float16 half8 __attribute__((ext_vector_type(8)));
typedef float f32x4 __attribute__((ext_vector_type(4)));

// ---------------- prep: all weight transposes + fp16 convert + cursor zero ----------------
// Wt layout: [wt1 128x256 | wt2 128x128 | wtg1 256x128 | wtg2 128x256 | wtg3 64x64]
__global__ __launch_bounds__(256)
void prep_kernel(const float* __restrict__ w1, const float* __restrict__ w2,
                 const float* __restrict__ g1w, const float* __restrict__ g2w,
                 const float* __restrict__ g3w, __half* __restrict__ wt,
                 int* __restrict__ cursor) {
  int idx = blockIdx.x * 256 + threadIdx.x;
  if (idx < NN) cursor[idx] = 0;
  const float* W; int K, N, li;
  if (idx < 32768)        { W = w1;  K = 256; N = 128; li = idx; }
  else if (idx < 49152)   { W = w2;  K = 128; N = 128; li = idx - 32768; }
  else if (idx < 81920)   { W = g1w; K = 128; N = 256; li = idx - 49152; }
  else if (idx < 114688)  { W = g2w; K = 256; N = 128; li = idx - 81920; }
  else if (idx < 118784)  { W = g3w; K = 64;  N = 64;  li = idx - 114688; }
  else return;
  int n = li / K, k = li - n * K;
  wt[idx] = __float2half_rn(W[(size_t)k * N + n]);
}

// ---------------- fused MLP + GAT1 linear: x -> h1 -> h2 -> xh1 (+ scores) ----------------
// One block = 64 rows. h1/h2 live only in LDS. Phase 3 overlays its 256-row weight
// staging onto [Bs12|h1s] (h1s dead) -> 50.2 KB LDS total -> 3 blocks/CU.
__global__ __launch_bounds__(256)
void mlp_gat1_fused(const float* __restrict__ x,
                    const __half* __restrict__ wt1,   // [128][256]
                    const float* __restrict__ b1,
                    const __half* __restrict__ wt2,   // [128][128]
                    const float* __restrict__ b2,
                    const __half* __restrict__ wtg1,  // [256][128]
                    const float* __restrict__ a_src, const float* __restrict__ a_dst,
                    __half* __restrict__ xh1,
                    float* __restrict__ s_src, float* __restrict__ s_dst) {
  constexpr int SA = 40;    // staging stride in halves (80 B, 16B-aligned)
  constexpr int SH = 136;   // h-tile stride in halves (2-way bank alias = free)
  // layout (halves): As 2560 | Bs12 5120 | h1s 8704 | h2s 8704  = 25088 (50.2 KB)
  // phase 3 weight staging Bs3 = Bs12 start, 10240 halves (overlaps h1s).
  __shared__ __align__(16) _Float16 smem[25088];
  _Float16* As   = smem;
  _Float16* Bs12 = smem + 2560;
  _Float16* h1s  = smem + 7680;
  _Float16* h2s  = smem + 16384;
  _Float16* Bs3  = Bs12;
  const int tid = threadIdx.x;
  const int bm = blockIdx.x * 64;
  const int wave = tid >> 6, lane = tid & 63;
  const int l16 = lane & 15, quad = lane >> 4;
  const int wm = (wave & 1) * 32;     // phase 1/2: 2x2 wave layout, tile 32x64
  const int wn = (wave >> 1) * 64;

  // ---- phase 1: h1 = relu(x @ w1 + b1), [64x128], K=256 ----
  {
    f32x4 acc[2][4] = {};
    for (int k0 = 0; k0 < 256; k0 += 32) {
      #pragma unroll
      for (int i = 0; i < 2; ++i) {
        int idx = tid + i * 256;
        int m = idx >> 3, q = idx & 7;
        int gm = bm + m;
        float4 v = make_float4(0.f, 0.f, 0.f, 0.f);
        if (gm < NN) v = *(const float4*)&x[(size_t)gm * 256 + k0 + q * 4];
        union { __half2 h2[2]; float2 f2; } u;
        u.h2[0] = __floats2half2_rn(v.x, v.y);
        u.h2[1] = __floats2half2_rn(v.z, v.w);
        *(float2*)&As[m * SA + q * 4] = u.f2;
      }
      #pragma unroll
      for (int i = 0; i < 2; ++i) {
        int idx = tid + i * 256;
        int n = idx >> 2, kq = (idx & 3) * 8;
        *(float4*)&Bs12[n * SA + kq] = *(const float4*)&wt1[(size_t)n * 256 + k0 + kq];
      }
      __syncthreads();
      half8 af[2], bf[4];
      #pragma unroll
      for (int mi = 0; mi < 2; ++mi)
        af[mi] = *(const half8*)&As[(wm + mi * 16 + l16) * SA + quad * 8];
      #pragma unroll
      for (int ni = 0; ni < 4; ++ni)
        bf[ni] = *(const half8*)&Bs12[(wn + ni * 16 + l16) * SA + quad * 8];
      #pragma unroll
      for (int mi = 0; mi < 2; ++mi)
        #pragma unroll
        for (int ni = 0; ni < 4; ++ni)
          acc[mi][ni] = __builtin_amdgcn_mfma_f32_16x16x32_f16(af[mi], bf[ni], acc[mi][ni], 0, 0, 0);
      __syncthreads();
    }
    #pragma unroll
    for (int mi = 0; mi < 2; ++mi)
      #pragma unroll
      for (int r = 0; r < 4; ++r) {
        int row = wm + mi * 16 + quad * 4 + r;
        #pragma unroll
        for (int ni = 0; ni < 4; ++ni) {
          int col = wn + ni * 16 + l16;
          float v = acc[mi][ni][r] + b1[col];
          v = fmaxf(v, 0.f);
          h1s[row * SH + col] = (_Float16)v;
        }
      }
  }
  __syncthreads();

  // ---- phase 2: h2 = relu(h1 @ w2 + b2), [64x128], K=128, A from LDS ----
  {
    f32x4 acc[2][4] = {};
    for (int k0 = 0; k0 < 128; k0 += 32) {
      #pragma unroll
      for (int i = 0; i < 2; ++i) {
        int idx = tid + i * 256;
        int n = idx >> 2, kq = (idx & 3) * 8;
        *(float4*)&Bs12[n * SA + kq] = *(const float4*)&wt2[(size_t)n * 128 + k0 + kq];
      }
      __syncthreads();
      half8 af[2], bf[4];
      #pragma unroll
      for (int mi = 0; mi < 2; ++mi)
        af[mi] = *(const half8*)&h1s[(wm + mi * 16 + l16) * SH + k0 + quad * 8];
      #pragma unroll
      for (int ni = 0; ni < 4; ++ni)
        bf[ni] = *(const half8*)&Bs12[(wn + ni * 16 + l16) * SA + quad * 8];
      #pragma unroll
      for (int mi = 0; mi < 2; ++mi)
        #pragma unroll
        for (int ni = 0; ni < 4; ++ni)
          acc[mi][ni] = __builtin_amdgcn_mfma_f32_16x16x32_f16(af[mi], bf[ni], acc[mi][ni], 0, 0, 0);
      __syncthreads();
    }
    #pragma unroll
    for (int mi = 0; mi < 2; ++mi)
      #pragma unroll
      for (int r = 0; r < 4; ++r) {
        int row = wm + mi * 16 + quad * 4 + r;
        #pragma unroll
        for (int ni = 0; ni < 4; ++ni) {
          int col = wn + ni * 16 + l16;
          float v = acc[mi][ni][r] + b2[col];
          v = fmaxf(v, 0.f);
          h2s[row * SH + col] = (_Float16)v;
        }
      }
  }
  __syncthreads();

  // ---- phase 3: xh1 = h2 @ wg1, [64x256], K=128; wave = head; Bs3 overlays h1s ----
  {
    f32x4 acc[4][4] = {};
    const int wn3 = wave * 64;
    for (int k0 = 0; k0 < 128; k0 += 32) {
      #pragma unroll
      for (int i = 0; i < 4; ++i) {
        int idx = tid + i * 256;
        int n = idx >> 2, kq = (idx & 3) * 8;
        *(float4*)&Bs3[n * SA + kq] = *(const float4*)&wtg1[(size_t)n * 128 + k0 + kq];
      }
      __syncthreads();
      half8 af[4], bf[4];
      #pragma unroll
      for (int mi = 0; mi < 4; ++mi)
        af[mi] = *(const half8*)&h2s[(mi * 16 + l16) * SH + k0 + quad * 8];
      #pragma unroll
      for (int ni = 0; ni < 4; ++ni)
        bf[ni] = *(const half8*)&Bs3[(wn3 + ni * 16 + l16) * SA + quad * 8];
      #pragma unroll
      for (int mi = 0; mi < 4; ++mi)
        #pragma unroll
        for (int ni = 0; ni < 4; ++ni)
          acc[mi][ni] = __builtin_amdgcn_mfma_f32_16x16x32_f16(af[mi], bf[ni], acc[mi][ni], 0, 0, 0);
      __syncthreads();
    }
    // epilogue: store xh1 fp16 + fused scores (head h = wave)
    float asv[4], adv[4];
    #pragma unroll
    for (int ni = 0; ni < 4; ++ni) {
      int d = ni * 16 + l16;
      asv[ni] = a_src[wave * 64 + d];
      adv[ni] = a_dst[wave * 64 + d];
    }
    #pragma unroll
    for (int mi = 0; mi < 4; ++mi) {
      #pragma unroll
      for (int r = 0; r < 4; ++r) {
        int gm = bm + mi * 16 + quad * 4 + r;
        float ss = 0.f, sd = 0.f;
        #pragma unroll
        for (int ni = 0; ni < 4; ++ni) {
          float v = acc[mi][ni][r];
          ss = fmaf(v, asv[ni], ss);
          sd = fmaf(v, adv[ni], sd);
          if (gm < NN) xh1[(size_t)gm * 256 + wn3 + ni * 16 + l16] = __float2half_rn(v);
        }
        #pragma unroll
        for (int off = 1; off < 16; off <<= 1) {
          ss += __shfl_xor(ss, off, 64);
          sd += __shfl_xor(sd, off, 64);
        }
        if (l16 == 0 && gm < NN) {
          s_src[gm * 4 + wave] = ss;
          s_dst[gm * 4 + wave] = sd;
        }
      }
    }
  }
}

// ---------------- MFMA GEMM (GAT2/GAT3): C = act(A @ B + bias), optional fused scores ----
template<int BM, int TN, int WR, int WC, int ACT, int OUTH, int AF32, int HS>
__global__ __launch_bounds__(256)
void mfma_gemm(const void* __restrict__ Av, const __half* __restrict__ Bt,
               const float* __restrict__ bias, void* __restrict__ Cv,
               const float* __restrict__ a_src, const float* __restrict__ a_dst,
               float* __restrict__ s_src, float* __restrict__ s_dst,
               int M, int N, int K) {
  constexpr int FM = BM / WR / 16;
  constexpr int FN = TN / WC / 16;
  constexpr int SA = 40;
  __shared__ __align__(16) _Float16 As[BM * SA];
  __shared__ __align__(16) _Float16 Bs[TN * SA];
  const int tid = threadIdx.x;
  const int bm = blockIdx.y * BM, bn = blockIdx.x * TN;
  const int wave = tid >> 6, lane = tid & 63;
  const int wm = (wave % WR) * (BM / WR);
  const int wn = (wave / WR) * (TN / WC);
  const int l16 = lane & 15, quad = lane >> 4;

  f32x4 acc[FM][FN] = {};

  for (int k0 = 0; k0 < K; k0 += 32) {
    if (AF32) {
      const float* A = (const float*)Av;
      #pragma unroll
      for (int i = 0; i < (BM * 8) / 256; ++i) {
        int idx = tid + i * 256;
        int m = idx >> 3, q = idx & 7;
        int gm = bm + m;
        float4 v = make_float4(0.f, 0.f, 0.f, 0.f);
        if (gm < M) v = *(const float4*)&A[(size_t)gm * K + k0 + q * 4];
        union { __half2 h2[2]; float2 f2; } u;
        u.h2[0] = __floats2half2_rn(v.x, v.y);
        u.h2[1] = __floats2half2_rn(v.z, v.w);
        *(float2*)&As[m * SA + q * 4] = u.f2;
      }
    } else {
      const __half* A = (const __half*)Av;
      #pragma unroll
      for (int i = 0; i < (BM * 4) / 256; ++i) {
        int idx = tid + i * 256;
        int m = idx >> 2, q = (idx & 3) * 8;
        int gm = bm + m;
        float4 raw = make_float4(0.f, 0.f, 0.f, 0.f);
        if (gm < M) raw = *(const float4*)&A[(size_t)gm * K + k0 + q];
        *(float4*)&As[m * SA + q] = raw;
      }
    }
    #pragma unroll
    for (int i = 0; i < (TN * 4) / 256; ++i) {
      int idx = tid + i * 256;
      int n = idx >> 2, kq = (idx & 3) * 8;
      float4 raw = *(const float4*)&Bt[(size_t)(bn + n) * K + k0 + kq];
      *(float4*)&Bs[n * SA + kq] = raw;
    }
    __syncthreads();
    half8 af[FM], bf[FN];
    #pragma unroll
    for (int mi = 0; mi < FM; ++mi)
      af[mi] = *(const half8*)&As[(wm + mi * 16 + l16) * SA + quad * 8];
    #pragma unroll
    for (int ni = 0; ni < FN; ++ni)
      bf[ni] = *(const half8*)&Bs[(wn + ni * 16 + l16) * SA + quad * 8];
    #pragma unroll
    for (int mi = 0; mi < FM; ++mi)
      #pragma unroll
      for (int ni = 0; ni < FN; ++ni)
        acc[mi][ni] = __builtin_amdgcn_mfma_f32_16x16x32_f16(af[mi], bf[ni], acc[mi][ni], 0, 0, 0);
    __syncthreads();
  }

  #pragma unroll
  for (int mi = 0; mi < FM; ++mi) {
    #pragma unroll
    for (int r = 0; r < 4; ++r) {
      int gm = bm + wm + mi * 16 + quad * 4 + r;
      if (gm >= M) continue;
      #pragma unroll
      for (int ni = 0; ni < FN; ++ni) {
        int gn = bn + wn + ni * 16 + l16;
        float v = acc[mi][ni][r];
        if (bias) v += bias[gn];
        if (ACT == 1) v = fmaxf(v, 0.f);
        if (OUTH) ((__half*)Cv)[(size_t)gm * N + gn] = __float2half_rn(v);
        else      ((float*)Cv)[(size_t)gm * N + gn] = v;
      }
    }
  }

  if (HS > 0) {
    const int h = (bn + wn) >> 6;
    float asv[FN], adv[FN];
    #pragma unroll
    for (int ni = 0; ni < FN; ++ni) {
      int d = ni * 16 + l16;
      asv[ni] = a_src[h * 64 + d];
      adv[ni] = a_dst[h * 64 + d];
    }
    #pragma unroll
    for (int mi = 0; mi < FM; ++mi) {
      #pragma unroll
      for (int r = 0; r < 4; ++r) {
        float ss = 0.f, sd = 0.f;
        #pragma unroll
        for (int ni = 0; ni < FN; ++ni) {
          float v = acc[mi][ni][r];
          ss = fmaf(v, asv[ni], ss);
          sd = fmaf(v, adv[ni], sd);
        }
        #pragma unroll
        for (int off = 1; off < 16; off <<= 1) {
          ss += __shfl_xor(ss, off, 64);
          sd += __shfl_xor(sd, off, 64);
        }
        int gm = bm + wm + mi * 16 + quad * 4 + r;
        if (l16 == 0 && gm < M) {
          s_src[gm * HS + h] = ss;
          s_dst[gm * HS + h] = sd;
        }
      }
    }
  }
}

// ---------------- CSR build over the NE real edges ----------------

__global__ __launch_bounds__(256)
void hist_kernel(const int* __restrict__ ei, int* __restrict__ cnt) {
  int e = blockIdx.x * blockDim.x + threadIdx.x;
  if (e >= NE) return;
  atomicAdd(&cnt[ei[NE + e]], 1);
}

__global__ __launch_bounds__(256)
void scan1_kernel(const int* __restrict__ in, int* __restrict__ out,
                  int* __restrict__ bsum, int n) {
  __shared__ int tmp[256];
  int t = threadIdx.x;
  int i = blockIdx.x * 256 + t;
  int v = (i < n) ? in[i] : 0;
  tmp[t] = v;
  __syncthreads();
  for (int off = 1; off < 256; off <<= 1) {
    int u = (t >= off) ? tmp[t - off] : 0;
    __syncthreads();
    tmp[t] += u;
    __syncthreads();
  }
  if (i <= n) out[i] = tmp[t] - v;
  if (t == 255) bsum[blockIdx.x] = tmp[255];
}

// scan2 merged in: every block redundantly scans the (<=256) block sums in LDS,
// then applies its exclusive prefix. Saves one kernel launch.
__global__ __launch_bounds__(256)
void scan3_kernel(int* __restrict__ out, const int* __restrict__ bsum,
                  int* __restrict__ cursor, int n, int nb) {
  __shared__ int tmp[256];
  int t = threadIdx.x;
  int bv = (t < nb) ? bsum[t] : 0;
  tmp[t] = bv;
  __syncthreads();
  for (int off = 1; off < 256; off <<= 1) {
    int u = (t >= off) ? tmp[t - off] : 0;
    __syncthreads();
    tmp[t] += u;
    __syncthreads();
  }
  int add = tmp[blockIdx.x] - ((blockIdx.x < nb) ? bsum[blockIdx.x] : 0);
  int i = blockIdx.x * 256 + t;
  if (i > n) return;
  int v = out[i] + add;
  out[i] = v;
  if (i < n) cursor[i] = v;
}

__global__ __launch_bounds__(256)
void scatter_kernel(const int* __restrict__ ei, int* __restrict__ cursor,
                    int* __restrict__ srcs) {
  int e = blockIdx.x * blockDim.x + threadIdx.x;
  if (e >= NE) return;
  int s = ei[e], d = ei[NE + e];
  int pos = atomicAdd(&cursor[d], 1);
  srcs[pos] = s;
}

// ---------------- GAT1 aggregate (H=4): one wave per node, LDS-staged weights ----
// At the random-gather service ceiling (~7 TB/s request-level) -- round-0 config.
__global__ __launch_bounds__(256)
void gat_aggregate4(const int* __restrict__ rowptr, const int* __restrict__ srcs,
                    const float* __restrict__ ssrc, const float* __restrict__ sdst,
                    const __half* __restrict__ xh, const float* __restrict__ bias,
                    __half* __restrict__ out) {
  constexpr int H = 4, HD = 256;
  __shared__ float wbuf[4][64 * H];
  __shared__ int sbuf[4][64];
  const int wslot = threadIdx.x >> 6;
  const int wid = (blockIdx.x * blockDim.x + threadIdx.x) >> 6;
  const int lane = threadIdx.x & 63;
  if (wid >= NN) return;
  const int n = wid;
  const int start = rowptr[n];
  const int end = rowptr[n + 1];
  const int h = lane >> 4;

  float sdv[H];
  #pragma unroll
  for (int hh = 0; hh < H; ++hh) sdv[hh] = sdst[n * H + hh];

  float z;
  float acc[H];
  {
    float wself[H];
    #pragma unroll
    for (int hh = 0; hh < H; ++hh) {
      float e = ssrc[n * H + hh] + sdv[hh];
      e = e >= 0.f ? e : 0.2f * e;
      wself[hh] = __expf(e);
    }
    float ws = wself[h];
    z = ws;
    const __half* xr = xh + (size_t)n * HD + lane * H;
    float2 raw = *(const float2*)xr;
    __half2 p0 = *(__half2*)&raw.x;
    __half2 p1 = *(__half2*)&raw.y;
    float2 f0 = __half22float2(p0), f1 = __half22float2(p1);
    acc[0] = ws * f0.x; acc[1] = ws * f0.y; acc[2] = ws * f1.x; acc[3] = ws * f1.y;
  }

  for (int base = start; base < end; base += 64) {
    int cnt = end - base;
    if (cnt > 64) cnt = 64;
    if (lane < cnt) {
      int s = srcs[base + lane];
      sbuf[wslot][lane] = s;
      float4 t = *(const float4*)&ssrc[s * 4];
      float ev[H] = {t.x, t.y, t.z, t.w};
      #pragma unroll
      for (int hh = 0; hh < H; ++hh) {
        float e = ev[hh] + sdv[hh];
        e = e >= 0.f ? e : 0.2f * e;
        wbuf[wslot][lane * H + hh] = __expf(e);
      }
    }
    #pragma unroll 4
    for (int j = 0; j < cnt; ++j) {
      int s = sbuf[wslot][j];
      float w = wbuf[wslot][j * H + h];
      z += w;
      const __half* xr = xh + (size_t)s * HD + lane * H;
      float2 raw = *(const float2*)xr;
      __half2 p0 = *(__half2*)&raw.x;
      __half2 p1 = *(__half2*)&raw.y;
      float2 f0 = __half22float2(p0), f1 = __half22float2(p1);
      acc[0] = fmaf(w, f0.x, acc[0]); acc[1] = fmaf(w, f0.y, acc[1]);
      acc[2] = fmaf(w, f1.x, acc[2]); acc[3] = fmaf(w, f1.y, acc[3]);
    }
  }
  const float inv = 1.f / z;

  float v[4];
  #pragma unroll
  for (int i = 0; i < 4; ++i) {
    v[i] = acc[i] * inv + bias[lane * 4 + i];
    v[i] = v[i] > 0.f ? v[i] : expm1f(v[i]);
  }
  union { __half2 h2[2]; float2 f2; } u;
  u.h2[0] = __floats2half2_rn(v[0], v[1]);
  u.h2[1] = __floats2half2_rn(v[2], v[3]);
  *(float2*)&out[(size_t)n * 256 + lane * 4] = u.f2;
}

// ---------------- GAT2/GAT3 aggregate: staged multi-edge consume ----------------
// Round-0 staging kept verbatim (coalesced srcs + wave-parallel weight exp in LDS).
// Consume loop processes NSUB staged edges per iteration: wave splits into NSUB
// groups of L8 lanes, each group covering one full row at 8 B/lane. Sub-group
// partials combined by a 1-2 step butterfly at the end.
// MODE 1: H=2, mean-over-heads + bias + ELU -> fp16 [NN][64]
// MODE 2: H=1, + bias -> fp32 [NN][64]
template<int H, int MODE>
__global__ __launch_bounds__(256)
void gat_aggregate_ms(const int* __restrict__ rowptr, const int* __restrict__ srcs,
                      const float* __restrict__ ssrc, const float* __restrict__ sdst,
                      const __half* __restrict__ xh, const float* __restrict__ bias,
                      void* __restrict__ outv) {
  constexpr int HD   = H * 64;      // halves per row: 128 / 64
  constexpr int L8   = HD / 4;      // lanes per edge-slot at 8 B/lane: 32 / 16
  constexpr int NSUB = 64 / L8;     // staged edges consumed per iteration: 2 / 4
  __shared__ float wbuf[4][64 * H];
  __shared__ int sbuf[4][64];
  const int wslot = threadIdx.x >> 6;
  const int wid = (blockIdx.x * blockDim.x + threadIdx.x) >> 6;
  const int lane = threadIdx.x & 63;
  if (wid >= NN) return;
  const int n = wid;
  const int start = rowptr[n];
  const int end = rowptr[n + 1];
  const int sub = lane / L8;        // which staged edge of the pack
  const int p = lane - sub * L8;    // 8 B slot within the row (cols p*4..p*4+3)
  const int hp = (p * 4) >> 6;      // head owning these columns (0 for H=1)

  float sdv[H];
  #pragma unroll
  for (int hh = 0; hh < H; ++hh) sdv[hh] = sdst[n * H + hh];

  float z = 0.f;
  float a0 = 0.f, a1 = 0.f, a2 = 0.f, a3 = 0.f;
  {
    // self loop: only sub 0 contributes (butterfly would double-count otherwise)
    float e = ssrc[n * H + hp] + sdv[hp];
    e = e >= 0.f ? e : 0.2f * e;
    float ws = __expf(e);
    if (sub == 0) {
      z = ws;
      float2 raw = *(const float2*)(xh + (size_t)n * HD + p * 4);
      __half2 q0 = *(__half2*)&raw.x, q1 = *(__half2*)&raw.y;
      float2 f0 = __half22float2(q0), f1 = __half22float2(q1);
      a0 = ws * f0.x; a1 = ws * f0.y; a2 = ws * f1.x; a3 = ws * f1.y;
    }
  }

  for (int base = start; base < end; base += 64) {
    int cnt = end - base;
    if (cnt > 64) cnt = 64;
    int cnt_pad = (cnt + NSUB - 1) & ~(NSUB - 1);
    if (lane < cnt) {
      int s = srcs[base + lane];
      sbuf[wslot][lane] = s;
      float ev[H];
      if (H == 2) {
        float2 t = *(const float2*)&ssrc[s * 2];
        ev[0] = t.x; ev[1] = t.y;
      } else {
        ev[0] = ssrc[s];
      }
      #pragma unroll
      for (int hh = 0; hh < H; ++hh) {
        float e = ev[hh] + sdv[hh];
        e = e >= 0.f ? e : 0.2f * e;
        wbuf[wslot][lane * H + hh] = __expf(e);
      }
    } else if (lane < cnt_pad) {
      sbuf[wslot][lane] = n;        // safe row, zero weight
      #pragma unroll
      for (int hh = 0; hh < H; ++hh) wbuf[wslot][lane * H + hh] = 0.f;
    }
    #pragma unroll 4
    for (int j = 0; j < cnt; j += NSUB) {
      int e = j + sub;
      int s = sbuf[wslot][e];
      float w = wbuf[wslot][e * H + hp];
      z += w;
      float2 raw = *(const float2*)(xh + (size_t)s * HD + p * 4);
      __half2 q0 = *(__half2*)&raw.x, q1 = *(__half2*)&raw.y;
      float2 f0 = __half22float2(q0), f1 = __half22float2(q1);
      a0 = fmaf(w, f0.x, a0); a1 = fmaf(w, f0.y, a1);
      a2 = fmaf(w, f1.x, a2); a3 = fmaf(w, f1.y, a3);
    }
  }

  // combine sub-group partials (1 step for H=2, 2 steps for H=1)
  #pragma unroll
  for (int m = L8; m < 64; m <<= 1) {
    z += __shfl_xor(z, m, 64);
    a0 += __shfl_xor(a0, m, 64);
    a1 += __shfl_xor(a1, m, 64);
    a2 += __shfl_xor(a2, m, 64);
    a3 += __shfl_xor(a3, m, 64);
  }
  const float inv = 1.f / z;

  if (MODE == 1) {
    // mean over 2 heads: lane p (head0, dims 4p..) pairs with lane p^16 (head1, same dims)
    float v0 = a0 * inv, v1 = a1 * inv, v2 = a2 * inv, v3 = a3 * inv;
    float o0 = __shfl_xor(v0, 16, 64);
    float o1 = __shfl_xor(v1, 16, 64);
    float o2 = __shfl_xor(v2, 16, 64);
    float o3 = __shfl_xor(v3, 16, 64);
    if (sub == 0 && hp == 0) {
      float m0 = (v0 + o0) * 0.5f + bias[p * 4 + 0];
      float m1 = (v1 + o1) * 0.5f + bias[p * 4 + 1];
      float m2 = (v2 + o2) * 0.5f + bias[p * 4 + 2];
      float m3 = (v3 + o3) * 0.5f + bias[p * 4 + 3];
      m0 = m0 > 0.f ? m0 : expm1f(m0);
      m1 = m1 > 0.f ? m1 : expm1f(m1);
      m2 = m2 > 0.f ? m2 : expm1f(m2);
      m3 = m3 > 0.f ? m3 : expm1f(m3);
      __half* out = (__half*)outv;
      union { __half2 h2[2]; float2 f2; } u;
      u.h2[0] = __floats2half2_rn(m0, m1);
      u.h2[1] = __floats2half2_rn(m2, m3);
      *(float2*)&out[(size_t)n * 64 + p * 4] = u.f2;
    }
  } else {
    if (sub == 0) {
      float* out = (float*)outv;
      float4 o = make_float4(a0 * inv + bias[p * 4 + 0],
                             a1 * inv + bias[p * 4 + 1],
                             a2 * inv + bias[p * 4 + 2],
                             a3 * inv + bias[p * 4 + 3]);
      *(float4*)&out[(size_t)n * 64 + p * 4] = o;
    }
  }
}

// ---------------- orchestration ----------------

extern "C" void kernel_launch(void* const* d_in, const int* in_sizes, int n_in,
                              void* d_out, int out_size, void* d_ws, size_t ws_size,
                              hipStream_t stream) {
  const float* x    = (const float*)d_in[0];
  const int*   ei   = (const int*)d_in[1];
  const float* w1   = (const float*)d_in[2];
  const float* b1   = (const float*)d_in[3];
  const float* w2   = (const float*)d_in[4];
  const float* b2   = (const float*)d_in[5];
  const float* g1w  = (const float*)d_in[6];
  const float* g1as = (const float*)d_in[7];
  const float* g1ad = (const float*)d_in[8];
  const float* g1b  = (const float*)d_in[9];
  const float* g2w  = (const float*)d_in[10];
  const float* g2as = (const float*)d_in[11];
  const float* g2ad = (const float*)d_in[12];
  const float* g2b  = (const float*)d_in[13];
  const float* g3w  = (const float*)d_in[14];
  const float* g3as = (const float*)d_in[15];
  const float* g3ad = (const float*)d_in[16];
  const float* g3b  = (const float*)d_in[17];
  float* out = (float*)d_out;

  float* ws   = (float*)d_ws;
  float* bufA = ws;
  float* bufB = bufA + (size_t)NN * 256;
  float* bufC = bufB + (size_t)NN * 256;
  float* ssrc = bufC + (size_t)NN * 256;     // NN*4
  float* sdst = ssrc + (size_t)NN * 4;       // NN*4
  int* rowptr = (int*)(sdst + (size_t)NN * 4);  // NN+1
  int* cursor = rowptr + (NN + 1);              // NN
  int* bsum   = cursor + NN;                    // 256
  int* srcs   = bsum + 256;                     // NE
  __half* wt   = (__half*)(srcs + NE);          // 118784 halves
  __half* wt1  = wt;                            // 128x256
  __half* wt2  = wt + 32768;                    // 128x128
  __half* wtg1 = wt + 49152;                    // 256x128
  __half* wtg2 = wt + 81920;                    // 128x256
  __half* wtg3 = wt + 114688;                   // 64x64

  __half* xh1 = (__half*)bufC;   // NN*256
  __half* a1  = (__half*)bufA;   // NN*256
  __half* xh2 = (__half*)bufB;   // NN*128
  __half* a2  = (__half*)bufC;   // NN*64  (xh1 dead)
  __half* xh3 = (__half*)bufB;   // NN*64  (xh2 dead)

  const int TB = 256;
  const int grid_m = ceil_div_h(NN, 64);        // 782
  const int egrid = ceil_div_h(NE, TB);
  const int sgrid = ceil_div_h(NN + 1, TB);
  const int wgrid = ceil_div_h(NN, 4);

  // ---- prep: weight convert + cursor zero ----
  prep_kernel<<<ceil_div_h(118784, TB), TB, 0, stream>>>(w1, w2, g1w, g2w, g3w, wt, cursor);

  // ---- CSR build (separate kernels: full oversubscription for hist/scatter) ----
  hist_kernel<<<egrid, TB, 0, stream>>>(ei, cursor);
  scan1_kernel<<<sgrid, TB, 0, stream>>>(cursor, rowptr, bsum, NN);
  scan3_kernel<<<sgrid, TB, 0, stream>>>(rowptr, bsum, cursor, NN, sgrid);
  scatter_kernel<<<egrid, TB, 0, stream>>>(ei, cursor, srcs);

  // ---- fused MLP + GAT1 linear: x -> h1 -> h2 -> xh1 (+scores) ----
  mlp_gat1_fused<<<grid_m, TB, 0, stream>>>(x, wt1, b1, wt2, b2, wtg1,
                                            g1as, g1ad, xh1, ssrc, sdst);
  gat_aggregate4<<<wgrid, TB, 0, stream>>>(rowptr, srcs, ssrc, sdst, xh1, g1b, a1);

  // ---- GAT2: 256 -> 2x64, mean, ELU; scores fused ----
  mfma_gemm<64, 128, 2, 2, 0, 1, 0, 2><<<dim3(1, grid_m), TB, 0, stream>>>(
      a1, wtg2, nullptr, xh2, g2as, g2ad, ssrc, sdst, NN, 128, 256);
  gat_aggregate_ms<2, 1><<<wgrid, TB, 0, stream>>>(
      rowptr, srcs, ssrc, sdst, xh2, g2b, a2);

  // ---- GAT3: 64 -> 1x64, identity mean, no ELU; scores fused ----
  mfma_gemm<64, 64, 4, 1, 0, 1, 0, 1><<<dim3(1, grid_m), TB, 0, stream>>>(
      a2, wtg3, nullptr, xh3, g3as, g3ad, ssrc, sdst, NN, 64, 64);
  gat_aggregate_ms<1, 2><<<wgrid, TB, 0, stream>>>(
      rowptr, srcs, ssrc, sdst, xh3, g3b, out);
}

// Round 7
// 391.576 us; speedup vs baseline: 1.1006x; 1.0125x over previous
//
#include <hip/hip_runtime.h>
#include <hip/hip_fp16.h>
#include <math.h>

#define NN 50000
#define NE 800000

static inline int ceil_div_h(int a, int b) { return (a + b - 1) / b; }

typedef _Float16 half8 __attribute__((ext_vector_type(8)));
typedef float f32x4 __attribute__((ext_vector_type(4)));

// ---------------- prep: all weight transposes + fp16 convert + cursor zero ----------------
// Wt layout: [wt1 128x256 | wt2 128x128 | wtg1 256x128 | wtg2 128x256 | wtg3 64x64]
__global__ __launch_bounds__(256)
void prep_kernel(const float* __restrict__ w1, const float* __restrict__ w2,
                 const float* __restrict__ g1w, const float* __restrict__ g2w,
                 const float* __restrict__ g3w, __half* __restrict__ wt,
                 int* __restrict__ cursor) {
  int idx = blockIdx.x * 256 + threadIdx.x;
  if (idx < NN) cursor[idx] = 0;
  const float* W; int K, N, li;
  if (idx < 32768)        { W = w1;  K = 256; N = 128; li = idx; }
  else if (idx < 49152)   { W = w2;  K = 128; N = 128; li = idx - 32768; }
  else if (idx < 81920)   { W = g1w; K = 128; N = 256; li = idx - 49152; }
  else if (idx < 114688)  { W = g2w; K = 256; N = 128; li = idx - 81920; }
  else if (idx < 118784)  { W = g3w; K = 64;  N = 64;  li = idx - 114688; }
  else return;
  int n = li / K, k = li - n * K;
  wt[idx] = __float2half_rn(W[(size_t)k * N + n]);
}

// ---------------- fused MLP + GAT1 linear: x -> h1 -> h2 -> xh1 (+ scores) ----------------
__global__ __launch_bounds__(256)
void mlp_gat1_fused(const float* __restrict__ x,
                    const __half* __restrict__ wt1,   // [128][256]
                    const float* __restrict__ b1,
                    const __half* __restrict__ wt2,   // [128][128]
                    const float* __restrict__ b2,
                    const __half* __restrict__ wtg1,  // [256][128]
                    const float* __restrict__ a_src, const float* __restrict__ a_dst,
                    __half* __restrict__ xh1,
                    float* __restrict__ s_src, float* __restrict__ s_dst) {
  constexpr int SA = 40;    // staging stride in halves (80 B, 16B-aligned)
  constexpr int SH = 136;   // h-tile stride in halves (2-way bank alias = free)
  __shared__ __align__(16) _Float16 smem[25088];
  _Float16* As   = smem;
  _Float16* Bs12 = smem + 2560;
  _Float16* h1s  = smem + 7680;
  _Float16* h2s  = smem + 16384;
  _Float16* Bs3  = Bs12;
  const int tid = threadIdx.x;
  const int bm = blockIdx.x * 64;
  const int wave = tid >> 6, lane = tid & 63;
  const int l16 = lane & 15, quad = lane >> 4;
  const int wm = (wave & 1) * 32;     // phase 1/2: 2x2 wave layout, tile 32x64
  const int wn = (wave >> 1) * 64;

  // ---- phase 1: h1 = relu(x @ w1 + b1), [64x128], K=256 ----
  {
    f32x4 acc[2][4] = {};
    for (int k0 = 0; k0 < 256; k0 += 32) {
      #pragma unroll
      for (int i = 0; i < 2; ++i) {
        int idx = tid + i * 256;
        int m = idx >> 3, q = idx & 7;
        int gm = bm + m;
        float4 v = make_float4(0.f, 0.f, 0.f, 0.f);
        if (gm < NN) v = *(const float4*)&x[(size_t)gm * 256 + k0 + q * 4];
        union { __half2 h2[2]; float2 f2; } u;
        u.h2[0] = __floats2half2_rn(v.x, v.y);
        u.h2[1] = __floats2half2_rn(v.z, v.w);
        *(float2*)&As[m * SA + q * 4] = u.f2;
      }
      #pragma unroll
      for (int i = 0; i < 2; ++i) {
        int idx = tid + i * 256;
        int n = idx >> 2, kq = (idx & 3) * 8;
        *(float4*)&Bs12[n * SA + kq] = *(const float4*)&wt1[(size_t)n * 256 + k0 + kq];
      }
      __syncthreads();
      half8 af[2], bf[4];
      #pragma unroll
      for (int mi = 0; mi < 2; ++mi)
        af[mi] = *(const half8*)&As[(wm + mi * 16 + l16) * SA + quad * 8];
      #pragma unroll
      for (int ni = 0; ni < 4; ++ni)
        bf[ni] = *(const half8*)&Bs12[(wn + ni * 16 + l16) * SA + quad * 8];
      #pragma unroll
      for (int mi = 0; mi < 2; ++mi)
        #pragma unroll
        for (int ni = 0; ni < 4; ++ni)
          acc[mi][ni] = __builtin_amdgcn_mfma_f32_16x16x32_f16(af[mi], bf[ni], acc[mi][ni], 0, 0, 0);
      __syncthreads();
    }
    #pragma unroll
    for (int mi = 0; mi < 2; ++mi)
      #pragma unroll
      for (int r = 0; r < 4; ++r) {
        int row = wm + mi * 16 + quad * 4 + r;
        #pragma unroll
        for (int ni = 0; ni < 4; ++ni) {
          int col = wn + ni * 16 + l16;
          float v = acc[mi][ni][r] + b1[col];
          v = fmaxf(v, 0.f);
          h1s[row * SH + col] = (_Float16)v;
        }
      }
  }
  __syncthreads();

  // ---- phase 2: h2 = relu(h1 @ w2 + b2), [64x128], K=128, A from LDS ----
  {
    f32x4 acc[2][4] = {};
    for (int k0 = 0; k0 < 128; k0 += 32) {
      #pragma unroll
      for (int i = 0; i < 2; ++i) {
        int idx = tid + i * 256;
        int n = idx >> 2, kq = (idx & 3) * 8;
        *(float4*)&Bs12[n * SA + kq] = *(const float4*)&wt2[(size_t)n * 128 + k0 + kq];
      }
      __syncthreads();
      half8 af[2], bf[4];
      #pragma unroll
      for (int mi = 0; mi < 2; ++mi)
        af[mi] = *(const half8*)&h1s[(wm + mi * 16 + l16) * SH + k0 + quad * 8];
      #pragma unroll
      for (int ni = 0; ni < 4; ++ni)
        bf[ni] = *(const half8*)&Bs12[(wn + ni * 16 + l16) * SA + quad * 8];
      #pragma unroll
      for (int mi = 0; mi < 2; ++mi)
        #pragma unroll
        for (int ni = 0; ni < 4; ++ni)
          acc[mi][ni] = __builtin_amdgcn_mfma_f32_16x16x32_f16(af[mi], bf[ni], acc[mi][ni], 0, 0, 0);
      __syncthreads();
    }
    #pragma unroll
    for (int mi = 0; mi < 2; ++mi)
      #pragma unroll
      for (int r = 0; r < 4; ++r) {
        int row = wm + mi * 16 + quad * 4 + r;
        #pragma unroll
        for (int ni = 0; ni < 4; ++ni) {
          int col = wn + ni * 16 + l16;
          float v = acc[mi][ni][r] + b2[col];
          v = fmaxf(v, 0.f);
          h2s[row * SH + col] = (_Float16)v;
        }
      }
  }
  __syncthreads();

  // ---- phase 3: xh1 = h2 @ wg1, [64x256], K=128; wave = head; Bs3 overlays h1s ----
  {
    f32x4 acc[4][4] = {};
    const int wn3 = wave * 64;
    for (int k0 = 0; k0 < 128; k0 += 32) {
      #pragma unroll
      for (int i = 0; i < 4; ++i) {
        int idx = tid + i * 256;
        int n = idx >> 2, kq = (idx & 3) * 8;
        *(float4*)&Bs3[n * SA + kq] = *(const float4*)&wtg1[(size_t)n * 128 + k0 + kq];
      }
      __syncthreads();
      half8 af[4], bf[4];
      #pragma unroll
      for (int mi = 0; mi < 4; ++mi)
        af[mi] = *(const half8*)&h2s[(mi * 16 + l16) * SH + k0 + quad * 8];
      #pragma unroll
      for (int ni = 0; ni < 4; ++ni)
        bf[ni] = *(const half8*)&Bs3[(wn3 + ni * 16 + l16) * SA + quad * 8];
      #pragma unroll
      for (int mi = 0; mi < 4; ++mi)
        #pragma unroll
        for (int ni = 0; ni < 4; ++ni)
          acc[mi][ni] = __builtin_amdgcn_mfma_f32_16x16x32_f16(af[mi], bf[ni], acc[mi][ni], 0, 0, 0);
      __syncthreads();
    }
    // epilogue: store xh1 fp16 + fused scores (head h = wave)
    float asv[4], adv[4];
    #pragma unroll
    for (int ni = 0; ni < 4; ++ni) {
      int d = ni * 16 + l16;
      asv[ni] = a_src[wave * 64 + d];
      adv[ni] = a_dst[wave * 64 + d];
    }
    #pragma unroll
    for (int mi = 0; mi < 4; ++mi) {
      #pragma unroll
      for (int r = 0; r < 4; ++r) {
        int gm = bm + mi * 16 + quad * 4 + r;
        float ss = 0.f, sd = 0.f;
        #pragma unroll
        for (int ni = 0; ni < 4; ++ni) {
          float v = acc[mi][ni][r];
          ss = fmaf(v, asv[ni], ss);
          sd = fmaf(v, adv[ni], sd);
          if (gm < NN) xh1[(size_t)gm * 256 + wn3 + ni * 16 + l16] = __float2half_rn(v);
        }
        #pragma unroll
        for (int off = 1; off < 16; off <<= 1) {
          ss += __shfl_xor(ss, off, 64);
          sd += __shfl_xor(sd, off, 64);
        }
        if (l16 == 0 && gm < NN) {
          s_src[gm * 4 + wave] = ss;
          s_dst[gm * 4 + wave] = sd;
        }
      }
    }
  }
}

// ---------------- MFMA GEMM (GAT2): C = A @ B, fp16 out, fused scores ----
template<int BM, int TN, int WR, int WC, int ACT, int OUTH, int AF32, int HS>
__global__ __launch_bounds__(256)
void mfma_gemm(const void* __restrict__ Av, const __half* __restrict__ Bt,
               const float* __restrict__ bias, void* __restrict__ Cv,
               const float* __restrict__ a_src, const float* __restrict__ a_dst,
               float* __restrict__ s_src, float* __restrict__ s_dst,
               int M, int N, int K) {
  constexpr int FM = BM / WR / 16;
  constexpr int FN = TN / WC / 16;
  constexpr int SA = 40;
  __shared__ __align__(16) _Float16 As[BM * SA];
  __shared__ __align__(16) _Float16 Bs[TN * SA];
  const int tid = threadIdx.x;
  const int bm = blockIdx.y * BM, bn = blockIdx.x * TN;
  const int wave = tid >> 6, lane = tid & 63;
  const int wm = (wave % WR) * (BM / WR);
  const int wn = (wave / WR) * (TN / WC);
  const int l16 = lane & 15, quad = lane >> 4;

  f32x4 acc[FM][FN] = {};

  for (int k0 = 0; k0 < K; k0 += 32) {
    if (AF32) {
      const float* A = (const float*)Av;
      #pragma unroll
      for (int i = 0; i < (BM * 8) / 256; ++i) {
        int idx = tid + i * 256;
        int m = idx >> 3, q = idx & 7;
        int gm = bm + m;
        float4 v = make_float4(0.f, 0.f, 0.f, 0.f);
        if (gm < M) v = *(const float4*)&A[(size_t)gm * K + k0 + q * 4];
        union { __half2 h2[2]; float2 f2; } u;
        u.h2[0] = __floats2half2_rn(v.x, v.y);
        u.h2[1] = __floats2half2_rn(v.z, v.w);
        *(float2*)&As[m * SA + q * 4] = u.f2;
      }
    } else {
      const __half* A = (const __half*)Av;
      #pragma unroll
      for (int i = 0; i < (BM * 4) / 256; ++i) {
        int idx = tid + i * 256;
        int m = idx >> 2, q = (idx & 3) * 8;
        int gm = bm + m;
        float4 raw = make_float4(0.f, 0.f, 0.f, 0.f);
        if (gm < M) raw = *(const float4*)&A[(size_t)gm * K + k0 + q];
        *(float4*)&As[m * SA + q] = raw;
      }
    }
    #pragma unroll
    for (int i = 0; i < (TN * 4) / 256; ++i) {
      int idx = tid + i * 256;
      int n = idx >> 2, kq = (idx & 3) * 8;
      float4 raw = *(const float4*)&Bt[(size_t)(bn + n) * K + k0 + kq];
      *(float4*)&Bs[n * SA + kq] = raw;
    }
    __syncthreads();
    half8 af[FM], bf[FN];
    #pragma unroll
    for (int mi = 0; mi < FM; ++mi)
      af[mi] = *(const half8*)&As[(wm + mi * 16 + l16) * SA + quad * 8];
    #pragma unroll
    for (int ni = 0; ni < FN; ++ni)
      bf[ni] = *(const half8*)&Bs[(wn + ni * 16 + l16) * SA + quad * 8];
    #pragma unroll
    for (int mi = 0; mi < FM; ++mi)
      #pragma unroll
      for (int ni = 0; ni < FN; ++ni)
        acc[mi][ni] = __builtin_amdgcn_mfma_f32_16x16x32_f16(af[mi], bf[ni], acc[mi][ni], 0, 0, 0);
    __syncthreads();
  }

  #pragma unroll
  for (int mi = 0; mi < FM; ++mi) {
    #pragma unroll
    for (int r = 0; r < 4; ++r) {
      int gm = bm + wm + mi * 16 + quad * 4 + r;
      if (gm >= M) continue;
      #pragma unroll
      for (int ni = 0; ni < FN; ++ni) {
        int gn = bn + wn + ni * 16 + l16;
        float v = acc[mi][ni][r];
        if (bias) v += bias[gn];
        if (ACT == 1) v = fmaxf(v, 0.f);
        if (OUTH) ((__half*)Cv)[(size_t)gm * N + gn] = __float2half_rn(v);
        else      ((float*)Cv)[(size_t)gm * N + gn] = v;
      }
    }
  }

  if (HS > 0) {
    const int h = (bn + wn) >> 6;
    float asv[FN], adv[FN];
    #pragma unroll
    for (int ni = 0; ni < FN; ++ni) {
      int d = ni * 16 + l16;
      asv[ni] = a_src[h * 64 + d];
      adv[ni] = a_dst[h * 64 + d];
    }
    #pragma unroll
    for (int mi = 0; mi < FM; ++mi) {
      #pragma unroll
      for (int r = 0; r < 4; ++r) {
        float ss = 0.f, sd = 0.f;
        #pragma unroll
        for (int ni = 0; ni < FN; ++ni) {
          float v = acc[mi][ni][r];
          ss = fmaf(v, asv[ni], ss);
          sd = fmaf(v, adv[ni], sd);
        }
        #pragma unroll
        for (int off = 1; off < 16; off <<= 1) {
          ss += __shfl_xor(ss, off, 64);
          sd += __shfl_xor(sd, off, 64);
        }
        int gm = bm + wm + mi * 16 + quad * 4 + r;
        if (l16 == 0 && gm < M) {
          s_src[gm * HS + h] = ss;
          s_dst[gm * HS + h] = sd;
        }
      }
    }
  }
}

// ---------------- CSR build over the NE real edges ----------------

// hist also records each edge's slot within its bucket (atomic return) so
// scatter needs no atomics.
__global__ __launch_bounds__(256)
void hist_kernel(const int* __restrict__ ei, int* __restrict__ cnt,
                 int* __restrict__ eslot) {
  int e = blockIdx.x * blockDim.x + threadIdx.x;
  if (e >= NE) return;
  eslot[e] = atomicAdd(&cnt[ei[NE + e]], 1);
}

__global__ __launch_bounds__(256)
void scan1_kernel(const int* __restrict__ in, int* __restrict__ out,
                  int* __restrict__ bsum, int n) {
  __shared__ int tmp[256];
  int t = threadIdx.x;
  int i = blockIdx.x * 256 + t;
  int v = (i < n) ? in[i] : 0;
  tmp[t] = v;
  __syncthreads();
  for (int off = 1; off < 256; off <<= 1) {
    int u = (t >= off) ? tmp[t - off] : 0;
    __syncthreads();
    tmp[t] += u;
    __syncthreads();
  }
  if (i <= n) out[i] = tmp[t] - v;
  if (t == 255) bsum[blockIdx.x] = tmp[255];
}

// scan2 merged: every block redundantly scans the (<=256) block sums in LDS.
__global__ __launch_bounds__(256)
void scan3_kernel(int* __restrict__ out, const int* __restrict__ bsum,
                  int n, int nb) {
  __shared__ int tmp[256];
  int t = threadIdx.x;
  int bv = (t < nb) ? bsum[t] : 0;
  tmp[t] = bv;
  __syncthreads();
  for (int off = 1; off < 256; off <<= 1) {
    int u = (t >= off) ? tmp[t - off] : 0;
    __syncthreads();
    tmp[t] += u;
    __syncthreads();
  }
  int add = tmp[blockIdx.x] - ((blockIdx.x < nb) ? bsum[blockIdx.x] : 0);
  int i = blockIdx.x * 256 + t;
  if (i > n) return;
  out[i] = out[i] + add;
}

// atomic-free scatter: pos = rowptr[d] + eslot[e]
__global__ __launch_bounds__(256)
void scatter_kernel(const int* __restrict__ ei, const int* __restrict__ rowptr,
                    const int* __restrict__ eslot, int* __restrict__ srcs) {
  int e = blockIdx.x * blockDim.x + threadIdx.x;
  if (e >= NE) return;
  int s = ei[e], d = ei[NE + e];
  srcs[rowptr[d] + eslot[e]] = s;
}

// ---------------- GAT1 aggregate (H=4): one wave per node, LDS-staged weights ----
// At the random-gather service ceiling (~6.7 TB/s request-level) -- round-0 config.
__global__ __launch_bounds__(256)
void gat_aggregate4(const int* __restrict__ rowptr, const int* __restrict__ srcs,
                    const float* __restrict__ ssrc, const float* __restrict__ sdst,
                    const __half* __restrict__ xh, const float* __restrict__ bias,
                    __half* __restrict__ out) {
  constexpr int H = 4, HD = 256;
  __shared__ float wbuf[4][64 * H];
  __shared__ int sbuf[4][64];
  const int wslot = threadIdx.x >> 6;
  const int wid = (blockIdx.x * blockDim.x + threadIdx.x) >> 6;
  const int lane = threadIdx.x & 63;
  if (wid >= NN) return;
  const int n = wid;
  const int start = rowptr[n];
  const int end = rowptr[n + 1];
  const int h = lane >> 4;

  float sdv[H];
  #pragma unroll
  for (int hh = 0; hh < H; ++hh) sdv[hh] = sdst[n * H + hh];

  float z;
  float acc[H];
  {
    float wself[H];
    #pragma unroll
    for (int hh = 0; hh < H; ++hh) {
      float e = ssrc[n * H + hh] + sdv[hh];
      e = e >= 0.f ? e : 0.2f * e;
      wself[hh] = __expf(e);
    }
    float ws = wself[h];
    z = ws;
    const __half* xr = xh + (size_t)n * HD + lane * H;
    float2 raw = *(const float2*)xr;
    __half2 p0 = *(__half2*)&raw.x;
    __half2 p1 = *(__half2*)&raw.y;
    float2 f0 = __half22float2(p0), f1 = __half22float2(p1);
    acc[0] = ws * f0.x; acc[1] = ws * f0.y; acc[2] = ws * f1.x; acc[3] = ws * f1.y;
  }

  for (int base = start; base < end; base += 64) {
    int cnt = end - base;
    if (cnt > 64) cnt = 64;
    if (lane < cnt) {
      int s = srcs[base + lane];
      sbuf[wslot][lane] = s;
      float4 t = *(const float4*)&ssrc[s * 4];
      float ev[H] = {t.x, t.y, t.z, t.w};
      #pragma unroll
      for (int hh = 0; hh < H; ++hh) {
        float e = ev[hh] + sdv[hh];
        e = e >= 0.f ? e : 0.2f * e;
        wbuf[wslot][lane * H + hh] = __expf(e);
      }
    }
    #pragma unroll 4
    for (int j = 0; j < cnt; ++j) {
      int s = sbuf[wslot][j];
      float w = wbuf[wslot][j * H + h];
      z += w;
      const __half* xr = xh + (size_t)s * HD + lane * H;
      float2 raw = *(const float2*)xr;
      __half2 p0 = *(__half2*)&raw.x;
      __half2 p1 = *(__half2*)&raw.y;
      float2 f0 = __half22float2(p0), f1 = __half22float2(p1);
      acc[0] = fmaf(w, f0.x, acc[0]); acc[1] = fmaf(w, f0.y, acc[1]);
      acc[2] = fmaf(w, f1.x, acc[2]); acc[3] = fmaf(w, f1.y, acc[3]);
    }
  }
  const float inv = 1.f / z;

  float v[4];
  #pragma unroll
  for (int i = 0; i < 4; ++i) {
    v[i] = acc[i] * inv + bias[lane * 4 + i];
    v[i] = v[i] > 0.f ? v[i] : expm1f(v[i]);
  }
  union { __half2 h2[2]; float2 f2; } u;
  u.h2[0] = __floats2half2_rn(v[0], v[1]);
  u.h2[1] = __floats2half2_rn(v[2], v[3]);
  *(float2*)&out[(size_t)n * 256 + lane * 4] = u.f2;
}

// ---------------- GAT2 aggregate + fused GAT3 linear & scores ----------------
// ms<2,1> staging/consume kept verbatim; epilogue computes a2 row in LDS (fp16),
// then xh3[n][d] = sum_k a2[k] * wtg3t[d][k] per lane d, plus GAT3 score reduce.
// Eliminates the 64x64 GEMM launch and the a2 global round-trip.
__global__ __launch_bounds__(256)
void gat_agg2_g3fused(const int* __restrict__ rowptr, const int* __restrict__ srcs,
                      const float* __restrict__ ssrc, const float* __restrict__ sdst,
                      const __half* __restrict__ xh,   // xh2 [NN][128]
                      const float* __restrict__ bias,  // g2b [64]
                      const __half* __restrict__ wtg3, // [64][64] transposed (out-major)
                      const float* __restrict__ a3s, const float* __restrict__ a3d,
                      __half* __restrict__ xh3,        // [NN][64] fp16
                      float* __restrict__ s3src, float* __restrict__ s3dst) {
  constexpr int H = 2, HD = 128, L8 = 32, NSUB = 2;
  __shared__ float wbuf[4][64 * H];
  __shared__ int sbuf[4][64];
  __shared__ __align__(16) __half a2h[4][64];
  const int wslot = threadIdx.x >> 6;
  const int wid = (blockIdx.x * blockDim.x + threadIdx.x) >> 6;
  const int lane = threadIdx.x & 63;
  if (wid >= NN) return;
  const int n = wid;
  const int start = rowptr[n];
  const int end = rowptr[n + 1];
  const int sub = lane / L8;        // which staged edge of the pack
  const int p = lane - sub * L8;    // 8 B slot within the row (cols p*4..p*4+3)
  const int hp = (p * 4) >> 6;      // head owning these columns

  float sdv[H];
  #pragma unroll
  for (int hh = 0; hh < H; ++hh) sdv[hh] = sdst[n * H + hh];

  float z = 0.f;
  float a0 = 0.f, a1 = 0.f, a2 = 0.f, a3 = 0.f;
  {
    float e = ssrc[n * H + hp] + sdv[hp];
    e = e >= 0.f ? e : 0.2f * e;
    float ws = __expf(e);
    if (sub == 0) {
      z = ws;
      float2 raw = *(const float2*)(xh + (size_t)n * HD + p * 4);
      __half2 q0 = *(__half2*)&raw.x, q1 = *(__half2*)&raw.y;
      float2 f0 = __half22float2(q0), f1 = __half22float2(q1);
      a0 = ws * f0.x; a1 = ws * f0.y; a2 = ws * f1.x; a3 = ws * f1.y;
    }
  }

  for (int base = start; base < end; base += 64) {
    int cnt = end - base;
    if (cnt > 64) cnt = 64;
    int cnt_pad = (cnt + NSUB - 1) & ~(NSUB - 1);
    if (lane < cnt) {
      int s = srcs[base + lane];
      sbuf[wslot][lane] = s;
      float2 t = *(const float2*)&ssrc[s * 2];
      float ev[H] = {t.x, t.y};
      #pragma unroll
      for (int hh = 0; hh < H; ++hh) {
        float e = ev[hh] + sdv[hh];
        e = e >= 0.f ? e : 0.2f * e;
        wbuf[wslot][lane * H + hh] = __expf(e);
      }
    } else if (lane < cnt_pad) {
      sbuf[wslot][lane] = n;        // safe row, zero weight
      #pragma unroll
      for (int hh = 0; hh < H; ++hh) wbuf[wslot][lane * H + hh] = 0.f;
    }
    #pragma unroll 4
    for (int j = 0; j < cnt; j += NSUB) {
      int e = j + sub;
      int s = sbuf[wslot][e];
      float w = wbuf[wslot][e * H + hp];
      z += w;
      float2 raw = *(const float2*)(xh + (size_t)s * HD + p * 4);
      __half2 q0 = *(__half2*)&raw.x, q1 = *(__half2*)&raw.y;
      float2 f0 = __half22float2(q0), f1 = __half22float2(q1);
      a0 = fmaf(w, f0.x, a0); a1 = fmaf(w, f0.y, a1);
      a2 = fmaf(w, f1.x, a2); a3 = fmaf(w, f1.y, a3);
    }
  }

  // combine sub partials (sub axis = lane^32)
  {
    z += __shfl_xor(z, 32, 64);
    a0 += __shfl_xor(a0, 32, 64);
    a1 += __shfl_xor(a1, 32, 64);
    a2 += __shfl_xor(a2, 32, 64);
    a3 += __shfl_xor(a3, 32, 64);
  }
  const float inv = 1.f / z;

  // mean over heads: lane p (head0 dims) pairs with lane p^16 (head1 same dims)
  float v0 = a0 * inv, v1 = a1 * inv, v2 = a2 * inv, v3 = a3 * inv;
  float o0 = __shfl_xor(v0, 16, 64);
  float o1 = __shfl_xor(v1, 16, 64);
  float o2 = __shfl_xor(v2, 16, 64);
  float o3 = __shfl_xor(v3, 16, 64);
  if (lane < 16) {
    float m0 = (v0 + o0) * 0.5f + bias[lane * 4 + 0];
    float m1 = (v1 + o1) * 0.5f + bias[lane * 4 + 1];
    float m2 = (v2 + o2) * 0.5f + bias[lane * 4 + 2];
    float m3 = (v3 + o3) * 0.5f + bias[lane * 4 + 3];
    m0 = m0 > 0.f ? m0 : expm1f(m0);
    m1 = m1 > 0.f ? m1 : expm1f(m1);
    m2 = m2 > 0.f ? m2 : expm1f(m2);
    m3 = m3 > 0.f ? m3 : expm1f(m3);
    *(__half2*)&a2h[wslot][lane * 4]     = __floats2half2_rn(m0, m1);
    *(__half2*)&a2h[wslot][lane * 4 + 2] = __floats2half2_rn(m2, m3);
  }
  __threadfence_block();   // order LDS write -> read (same wave, own wslot row)

  // ---- fused GAT3 linear: xh3[n][lane] = sum_k a2[k] * wtg3[lane][k] ----
  float acc3 = 0.f;
  {
    const float4* arow = (const float4*)&a2h[wslot][0];          // 8 x 16B (broadcast)
    const float4* wrow = (const float4*)(wtg3 + (size_t)lane * 64);
    #pragma unroll
    for (int i = 0; i < 8; ++i) {
      float4 av = arow[i];
      float4 wv = wrow[i];
      const __half2* ah = (const __half2*)&av;
      const __half2* wh = (const __half2*)&wv;
      #pragma unroll
      for (int j = 0; j < 4; ++j) {
        float2 af = __half22float2(ah[j]);
        float2 wf = __half22float2(wh[j]);
        acc3 = fmaf(af.x, wf.x, acc3);
        acc3 = fmaf(af.y, wf.y, acc3);
      }
    }
  }
  // GAT3 scores (1 head): reduce over the 64 dims
  float s3s = acc3 * a3s[lane];
  float s3d = acc3 * a3d[lane];
  #pragma unroll
  for (int off = 1; off < 64; off <<= 1) {
    s3s += __shfl_xor(s3s, off, 64);
    s3d += __shfl_xor(s3d, off, 64);
  }
  if (lane == 0) {
    s3src[n] = s3s;
    s3dst[n] = s3d;
  }
  xh3[(size_t)n * 64 + lane] = __float2half_rn(acc3);
}

// ---------------- GAT3 aggregate (H=1): staged multi-edge consume ----------------
__global__ __launch_bounds__(256)
void gat_aggregate3(const int* __restrict__ rowptr, const int* __restrict__ srcs,
                    const float* __restrict__ ssrc, const float* __restrict__ sdst,
                    const __half* __restrict__ xh,   // xh3 [NN][64]
                    const float* __restrict__ bias,  // g3b
                    float* __restrict__ out) {
  constexpr int HD = 64, L8 = 16, NSUB = 4;
  __shared__ float wbuf[4][64];
  __shared__ int sbuf[4][64];
  const int wslot = threadIdx.x >> 6;
  const int wid = (blockIdx.x * blockDim.x + threadIdx.x) >> 6;
  const int lane = threadIdx.x & 63;
  if (wid >= NN) return;
  const int n = wid;
  const int start = rowptr[n];
  const int end = rowptr[n + 1];
  const int sub = lane / L8;
  const int p = lane - sub * L8;

  const float sdv = sdst[n];

  float z = 0.f;
  float a0 = 0.f, a1 = 0.f, a2 = 0.f, a3 = 0.f;
  {
    float e = ssrc[n] + sdv;
    e = e >= 0.f ? e : 0.2f * e;
    float ws = __expf(e);
    if (sub == 0) {
      z = ws;
      float2 raw = *(const float2*)(xh + (size_t)n * HD + p * 4);
      __half2 q0 = *(__half2*)&raw.x, q1 = *(__half2*)&raw.y;
      float2 f0 = __half22float2(q0), f1 = __half22float2(q1);
      a0 = ws * f0.x; a1 = ws * f0.y; a2 = ws * f1.x; a3 = ws * f1.y;
    }
  }

  for (int base = start; base < end; base += 64) {
    int cnt = end - base;
    if (cnt > 64) cnt = 64;
    int cnt_pad = (cnt + NSUB - 1) & ~(NSUB - 1);
    if (lane < cnt) {
      int s = srcs[base + lane];
      sbuf[wslot][lane] = s;
      float e = ssrc[s] + sdv;
      e = e >= 0.f ? e : 0.2f * e;
      wbuf[wslot][lane] = __expf(e);
    } else if (lane < cnt_pad) {
      sbuf[wslot][lane] = n;
      wbuf[wslot][lane] = 0.f;
    }
    #pragma unroll 4
    for (int j = 0; j < cnt; j += NSUB) {
      int e = j + sub;
      int s = sbuf[wslot][e];
      float w = wbuf[wslot][e];
      z += w;
      float2 raw = *(const float2*)(xh + (size_t)s * HD + p * 4);
      __half2 q0 = *(__half2*)&raw.x, q1 = *(__half2*)&raw.y;
      float2 f0 = __half22float2(q0), f1 = __half22float2(q1);
      a0 = fmaf(w, f0.x, a0); a1 = fmaf(w, f0.y, a1);
      a2 = fmaf(w, f1.x, a2); a3 = fmaf(w, f1.y, a3);
    }
  }

  #pragma unroll
  for (int m = L8; m < 64; m <<= 1) {
    z += __shfl_xor(z, m, 64);
    a0 += __shfl_xor(a0, m, 64);
    a1 += __shfl_xor(a1, m, 64);
    a2 += __shfl_xor(a2, m, 64);
    a3 += __shfl_xor(a3, m, 64);
  }
  const float inv = 1.f / z;

  if (sub == 0) {
    float4 o = make_float4(a0 * inv + bias[p * 4 + 0],
                           a1 * inv + bias[p * 4 + 1],
                           a2 * inv + bias[p * 4 + 2],
                           a3 * inv + bias[p * 4 + 3]);
    *(float4*)&out[(size_t)n * 64 + p * 4] = o;
  }
}

// ---------------- orchestration ----------------

extern "C" void kernel_launch(void* const* d_in, const int* in_sizes, int n_in,
                              void* d_out, int out_size, void* d_ws, size_t ws_size,
                              hipStream_t stream) {
  const float* x    = (const float*)d_in[0];
  const int*   ei   = (const int*)d_in[1];
  const float* w1   = (const float*)d_in[2];
  const float* b1   = (const float*)d_in[3];
  const float* w2   = (const float*)d_in[4];
  const float* b2   = (const float*)d_in[5];
  const float* g1w  = (const float*)d_in[6];
  const float* g1as = (const float*)d_in[7];
  const float* g1ad = (const float*)d_in[8];
  const float* g1b  = (const float*)d_in[9];
  const float* g2w  = (const float*)d_in[10];
  const float* g2as = (const float*)d_in[11];
  const float* g2ad = (const float*)d_in[12];
  const float* g2b  = (const float*)d_in[13];
  const float* g3w  = (const float*)d_in[14];
  const float* g3as = (const float*)d_in[15];
  const float* g3ad = (const float*)d_in[16];
  const float* g3b  = (const float*)d_in[17];
  float* out = (float*)d_out;

  float* ws   = (float*)d_ws;
  float* bufA = ws;
  float* bufB = bufA + (size_t)NN * 256;
  float* bufC = bufB + (size_t)NN * 256;
  float* ssrc = bufC + (size_t)NN * 256;     // NN*4
  float* sdst = ssrc + (size_t)NN * 4;       // NN*4
  int* rowptr = (int*)(sdst + (size_t)NN * 4);  // NN+1
  int* cursor = rowptr + (NN + 1);              // NN
  int* bsum   = cursor + NN;                    // 256
  int* srcs   = bsum + 256;                     // NE
  __half* wt   = (__half*)(srcs + NE);          // 118784 halves
  __half* wt1  = wt;                            // 128x256
  __half* wt2  = wt + 32768;                    // 128x128
  __half* wtg1 = wt + 49152;                    // 256x128
  __half* wtg2 = wt + 81920;                    // 128x256
  __half* wtg3 = wt + 114688;                   // 64x64

  __half* xh1 = (__half*)bufC;   // NN*256
  __half* a1  = (__half*)bufA;   // NN*256
  __half* xh2 = (__half*)bufB;   // NN*128
  __half* xh3 = (__half*)bufA;   // NN*64  (a1 dead after gemm2)
  int* eslot  = (int*)bufB;      // NE ints (bufB dead during CSR build)
  float* s3src = ssrc + 2 * NN;  // upper half of GAT1 score region (dead)
  float* s3dst = sdst + 2 * NN;

  const int TB = 256;
  const int grid_m = ceil_div_h(NN, 64);        // 782
  const int egrid = ceil_div_h(NE, TB);
  const int sgrid = ceil_div_h(NN + 1, TB);
  const int wgrid = ceil_div_h(NN, 4);

  // ---- prep: weight convert + cursor zero ----
  prep_kernel<<<ceil_div_h(118784, TB), TB, 0, stream>>>(w1, w2, g1w, g2w, g3w, wt, cursor);

  // ---- CSR build ----
  hist_kernel<<<egrid, TB, 0, stream>>>(ei, cursor, eslot);
  scan1_kernel<<<sgrid, TB, 0, stream>>>(cursor, rowptr, bsum, NN);
  scan3_kernel<<<sgrid, TB, 0, stream>>>(rowptr, bsum, NN, sgrid);
  scatter_kernel<<<egrid, TB, 0, stream>>>(ei, rowptr, eslot, srcs);

  // ---- fused MLP + GAT1 linear: x -> h1 -> h2 -> xh1 (+scores) ----
  mlp_gat1_fused<<<grid_m, TB, 0, stream>>>(x, wt1, b1, wt2, b2, wtg1,
                                            g1as, g1ad, xh1, ssrc, sdst);
  gat_aggregate4<<<wgrid, TB, 0, stream>>>(rowptr, srcs, ssrc, sdst, xh1, g1b, a1);

  // ---- GAT2 linear: 256 -> 2x64 + scores ----
  mfma_gemm<64, 128, 2, 2, 0, 1, 0, 2><<<dim3(1, grid_m), TB, 0, stream>>>(
      a1, wtg2, nullptr, xh2, g2as, g2ad, ssrc, sdst, NN, 128, 256);

  // ---- GAT2 aggregate + fused GAT3 linear & scores ----
  gat_agg2_g3fused<<<wgrid, TB, 0, stream>>>(
      rowptr, srcs, ssrc, sdst, xh2, g2b, wtg3, g3as, g3ad, xh3, s3src, s3dst);

  // ---- GAT3 aggregate -> out ----
  gat_aggregate3<<<wgrid, TB, 0, stream>>>(
      rowptr, srcs, s3src, s3dst, xh3, g3b, out);
}

// Round 8
// 382.969 us; speedup vs baseline: 1.1254x; 1.0225x over previous
//
#include <hip/hip_runtime.h>
#include <hip/hip_fp16.h>
#include <math.h>

#define NN 50000
#define NE 800000

static inline int ceil_div_h(int a, int b) { return (a + b - 1) / b; }

typedef _Float16 half8 __attribute__((ext_vector_type(8)));
typedef float f32x4 __attribute__((ext_vector_type(4)));

// fast ELU negative branch: __expf(v)-1 == expm1f(v) within ~1e-7 abs for v<=0;
// fp16 output quantization (2.4e-4) dominates. Verified bit-identical absmax (r2).
__device__ inline float elu_neg(float v) { return __expf(v) - 1.f; }

// ---------------- prep: all weight transposes + fp16 convert + cursor zero ----------------
// Wt layout: [wt1 128x256 | wt2 128x128 | wtg1 256x128 | wtg2 128x256 | wtg3 64x64]
__global__ __launch_bounds__(256)
void prep_kernel(const float* __restrict__ w1, const float* __restrict__ w2,
                 const float* __restrict__ g1w, const float* __restrict__ g2w,
                 const float* __restrict__ g3w, __half* __restrict__ wt,
                 int* __restrict__ cursor) {
  int idx = blockIdx.x * 256 + threadIdx.x;
  if (idx < NN) cursor[idx] = 0;
  const float* W; int K, N, li;
  if (idx < 32768)        { W = w1;  K = 256; N = 128; li = idx; }
  else if (idx < 49152)   { W = w2;  K = 128; N = 128; li = idx - 32768; }
  else if (idx < 81920)   { W = g1w; K = 128; N = 256; li = idx - 49152; }
  else if (idx < 114688)  { W = g2w; K = 256; N = 128; li = idx - 81920; }
  else if (idx < 118784)  { W = g3w; K = 64;  N = 64;  li = idx - 114688; }
  else return;
  int n = li / K, k = li - n * K;
  wt[idx] = __float2half_rn(W[(size_t)k * N + n]);
}

// ---------------- fused MLP + GAT1 linear: x -> h1 -> h2 -> xh1 (+ scores) ----------------
__global__ __launch_bounds__(256)
void mlp_gat1_fused(const float* __restrict__ x,
                    const __half* __restrict__ wt1,   // [128][256]
                    const float* __restrict__ b1,
                    const __half* __restrict__ wt2,   // [128][128]
                    const float* __restrict__ b2,
                    const __half* __restrict__ wtg1,  // [256][128]
                    const float* __restrict__ a_src, const float* __restrict__ a_dst,
                    __half* __restrict__ xh1,
                    float* __restrict__ s_src, float* __restrict__ s_dst) {
  constexpr int SA = 40;    // staging stride in halves (80 B, 16B-aligned)
  constexpr int SH = 136;   // h-tile stride in halves (2-way bank alias = free)
  __shared__ __align__(16) _Float16 smem[25088];
  _Float16* As   = smem;
  _Float16* Bs12 = smem + 2560;
  _Float16* h1s  = smem + 7680;
  _Float16* h2s  = smem + 16384;
  _Float16* Bs3  = Bs12;
  const int tid = threadIdx.x;
  const int bm = blockIdx.x * 64;
  const int wave = tid >> 6, lane = tid & 63;
  const int l16 = lane & 15, quad = lane >> 4;
  const int wm = (wave & 1) * 32;     // phase 1/2: 2x2 wave layout, tile 32x64
  const int wn = (wave >> 1) * 64;

  // ---- phase 1: h1 = relu(x @ w1 + b1), [64x128], K=256 ----
  {
    f32x4 acc[2][4] = {};
    for (int k0 = 0; k0 < 256; k0 += 32) {
      #pragma unroll
      for (int i = 0; i < 2; ++i) {
        int idx = tid + i * 256;
        int m = idx >> 3, q = idx & 7;
        int gm = bm + m;
        float4 v = make_float4(0.f, 0.f, 0.f, 0.f);
        if (gm < NN) v = *(const float4*)&x[(size_t)gm * 256 + k0 + q * 4];
        union { __half2 h2[2]; float2 f2; } u;
        u.h2[0] = __floats2half2_rn(v.x, v.y);
        u.h2[1] = __floats2half2_rn(v.z, v.w);
        *(float2*)&As[m * SA + q * 4] = u.f2;
      }
      #pragma unroll
      for (int i = 0; i < 2; ++i) {
        int idx = tid + i * 256;
        int n = idx >> 2, kq = (idx & 3) * 8;
        *(float4*)&Bs12[n * SA + kq] = *(const float4*)&wt1[(size_t)n * 256 + k0 + kq];
      }
      __syncthreads();
      half8 af[2], bf[4];
      #pragma unroll
      for (int mi = 0; mi < 2; ++mi)
        af[mi] = *(const half8*)&As[(wm + mi * 16 + l16) * SA + quad * 8];
      #pragma unroll
      for (int ni = 0; ni < 4; ++ni)
        bf[ni] = *(const half8*)&Bs12[(wn + ni * 16 + l16) * SA + quad * 8];
      #pragma unroll
      for (int mi = 0; mi < 2; ++mi)
        #pragma unroll
        for (int ni = 0; ni < 4; ++ni)
          acc[mi][ni] = __builtin_amdgcn_mfma_f32_16x16x32_f16(af[mi], bf[ni], acc[mi][ni], 0, 0, 0);
      __syncthreads();
    }
    #pragma unroll
    for (int mi = 0; mi < 2; ++mi)
      #pragma unroll
      for (int r = 0; r < 4; ++r) {
        int row = wm + mi * 16 + quad * 4 + r;
        #pragma unroll
        for (int ni = 0; ni < 4; ++ni) {
          int col = wn + ni * 16 + l16;
          float v = acc[mi][ni][r] + b1[col];
          v = fmaxf(v, 0.f);
          h1s[row * SH + col] = (_Float16)v;
        }
      }
  }
  __syncthreads();

  // ---- phase 2: h2 = relu(h1 @ w2 + b2), [64x128], K=128, A from LDS ----
  {
    f32x4 acc[2][4] = {};
    for (int k0 = 0; k0 < 128; k0 += 32) {
      #pragma unroll
      for (int i = 0; i < 2; ++i) {
        int idx = tid + i * 256;
        int n = idx >> 2, kq = (idx & 3) * 8;
        *(float4*)&Bs12[n * SA + kq] = *(const float4*)&wt2[(size_t)n * 128 + k0 + kq];
      }
      __syncthreads();
      half8 af[2], bf[4];
      #pragma unroll
      for (int mi = 0; mi < 2; ++mi)
        af[mi] = *(const half8*)&h1s[(wm + mi * 16 + l16) * SH + k0 + quad * 8];
      #pragma unroll
      for (int ni = 0; ni < 4; ++ni)
        bf[ni] = *(const half8*)&Bs12[(wn + ni * 16 + l16) * SA + quad * 8];
      #pragma unroll
      for (int mi = 0; mi < 2; ++mi)
        #pragma unroll
        for (int ni = 0; ni < 4; ++ni)
          acc[mi][ni] = __builtin_amdgcn_mfma_f32_16x16x32_f16(af[mi], bf[ni], acc[mi][ni], 0, 0, 0);
      __syncthreads();
    }
    #pragma unroll
    for (int mi = 0; mi < 2; ++mi)
      #pragma unroll
      for (int r = 0; r < 4; ++r) {
        int row = wm + mi * 16 + quad * 4 + r;
        #pragma unroll
        for (int ni = 0; ni < 4; ++ni) {
          int col = wn + ni * 16 + l16;
          float v = acc[mi][ni][r] + b2[col];
          v = fmaxf(v, 0.f);
          h2s[row * SH + col] = (_Float16)v;
        }
      }
  }
  __syncthreads();

  // ---- phase 3: xh1 = h2 @ wg1, [64x256], K=128; wave = head; Bs3 overlays h1s ----
  {
    f32x4 acc[4][4] = {};
    const int wn3 = wave * 64;
    for (int k0 = 0; k0 < 128; k0 += 32) {
      #pragma unroll
      for (int i = 0; i < 4; ++i) {
        int idx = tid + i * 256;
        int n = idx >> 2, kq = (idx & 3) * 8;
        *(float4*)&Bs3[n * SA + kq] = *(const float4*)&wtg1[(size_t)n * 128 + k0 + kq];
      }
      __syncthreads();
      half8 af[4], bf[4];
      #pragma unroll
      for (int mi = 0; mi < 4; ++mi)
        af[mi] = *(const half8*)&h2s[(mi * 16 + l16) * SH + k0 + quad * 8];
      #pragma unroll
      for (int ni = 0; ni < 4; ++ni)
        bf[ni] = *(const half8*)&Bs3[(wn3 + ni * 16 + l16) * SA + quad * 8];
      #pragma unroll
      for (int mi = 0; mi < 4; ++mi)
        #pragma unroll
        for (int ni = 0; ni < 4; ++ni)
          acc[mi][ni] = __builtin_amdgcn_mfma_f32_16x16x32_f16(af[mi], bf[ni], acc[mi][ni], 0, 0, 0);
      __syncthreads();
    }
    // epilogue: store xh1 fp16 + fused scores (head h = wave)
    float asv[4], adv[4];
    #pragma unroll
    for (int ni = 0; ni < 4; ++ni) {
      int d = ni * 16 + l16;
      asv[ni] = a_src[wave * 64 + d];
      adv[ni] = a_dst[wave * 64 + d];
    }
    #pragma unroll
    for (int mi = 0; mi < 4; ++mi) {
      #pragma unroll
      for (int r = 0; r < 4; ++r) {
        int gm = bm + mi * 16 + quad * 4 + r;
        float ss = 0.f, sd = 0.f;
        #pragma unroll
        for (int ni = 0; ni < 4; ++ni) {
          float v = acc[mi][ni][r];
          ss = fmaf(v, asv[ni], ss);
          sd = fmaf(v, adv[ni], sd);
          if (gm < NN) xh1[(size_t)gm * 256 + wn3 + ni * 16 + l16] = __float2half_rn(v);
        }
        #pragma unroll
        for (int off = 1; off < 16; off <<= 1) {
          ss += __shfl_xor(ss, off, 64);
          sd += __shfl_xor(sd, off, 64);
        }
        if (l16 == 0 && gm < NN) {
          s_src[gm * 4 + wave] = ss;
          s_dst[gm * 4 + wave] = sd;
        }
      }
    }
  }
}

// ---------------- MFMA GEMM (GAT2): C = A @ B, fp16 out, fused scores ----
template<int BM, int TN, int WR, int WC, int ACT, int OUTH, int AF32, int HS>
__global__ __launch_bounds__(256)
void mfma_gemm(const void* __restrict__ Av, const __half* __restrict__ Bt,
               const float* __restrict__ bias, void* __restrict__ Cv,
               const float* __restrict__ a_src, const float* __restrict__ a_dst,
               float* __restrict__ s_src, float* __restrict__ s_dst,
               int M, int N, int K) {
  constexpr int FM = BM / WR / 16;
  constexpr int FN = TN / WC / 16;
  constexpr int SA = 40;
  __shared__ __align__(16) _Float16 As[BM * SA];
  __shared__ __align__(16) _Float16 Bs[TN * SA];
  const int tid = threadIdx.x;
  const int bm = blockIdx.y * BM, bn = blockIdx.x * TN;
  const int wave = tid >> 6, lane = tid & 63;
  const int wm = (wave % WR) * (BM / WR);
  const int wn = (wave / WR) * (TN / WC);
  const int l16 = lane & 15, quad = lane >> 4;

  f32x4 acc[FM][FN] = {};

  for (int k0 = 0; k0 < K; k0 += 32) {
    if (AF32) {
      const float* A = (const float*)Av;
      #pragma unroll
      for (int i = 0; i < (BM * 8) / 256; ++i) {
        int idx = tid + i * 256;
        int m = idx >> 3, q = idx & 7;
        int gm = bm + m;
        float4 v = make_float4(0.f, 0.f, 0.f, 0.f);
        if (gm < M) v = *(const float4*)&A[(size_t)gm * K + k0 + q * 4];
        union { __half2 h2[2]; float2 f2; } u;
        u.h2[0] = __floats2half2_rn(v.x, v.y);
        u.h2[1] = __floats2half2_rn(v.z, v.w);
        *(float2*)&As[m * SA + q * 4] = u.f2;
      }
    } else {
      const __half* A = (const __half*)Av;
      #pragma unroll
      for (int i = 0; i < (BM * 4) / 256; ++i) {
        int idx = tid + i * 256;
        int m = idx >> 2, q = (idx & 3) * 8;
        int gm = bm + m;
        float4 raw = make_float4(0.f, 0.f, 0.f, 0.f);
        if (gm < M) raw = *(const float4*)&A[(size_t)gm * K + k0 + q];
        *(float4*)&As[m * SA + q] = raw;
      }
    }
    #pragma unroll
    for (int i = 0; i < (TN * 4) / 256; ++i) {
      int idx = tid + i * 256;
      int n = idx >> 2, kq = (idx & 3) * 8;
      float4 raw = *(const float4*)&Bt[(size_t)(bn + n) * K + k0 + kq];
      *(float4*)&Bs[n * SA + kq] = raw;
    }
    __syncthreads();
    half8 af[FM], bf[FN];
    #pragma unroll
    for (int mi = 0; mi < FM; ++mi)
      af[mi] = *(const half8*)&As[(wm + mi * 16 + l16) * SA + quad * 8];
    #pragma unroll
    for (int ni = 0; ni < FN; ++ni)
      bf[ni] = *(const half8*)&Bs[(wn + ni * 16 + l16) * SA + quad * 8];
    #pragma unroll
    for (int mi = 0; mi < FM; ++mi)
      #pragma unroll
      for (int ni = 0; ni < FN; ++ni)
        acc[mi][ni] = __builtin_amdgcn_mfma_f32_16x16x32_f16(af[mi], bf[ni], acc[mi][ni], 0, 0, 0);
    __syncthreads();
  }

  #pragma unroll
  for (int mi = 0; mi < FM; ++mi) {
    #pragma unroll
    for (int r = 0; r < 4; ++r) {
      int gm = bm + wm + mi * 16 + quad * 4 + r;
      if (gm >= M) continue;
      #pragma unroll
      for (int ni = 0; ni < FN; ++ni) {
        int gn = bn + wn + ni * 16 + l16;
        float v = acc[mi][ni][r];
        if (bias) v += bias[gn];
        if (ACT == 1) v = fmaxf(v, 0.f);
        if (OUTH) ((__half*)Cv)[(size_t)gm * N + gn] = __float2half_rn(v);
        else      ((float*)Cv)[(size_t)gm * N + gn] = v;
      }
    }
  }

  if (HS > 0) {
    const int h = (bn + wn) >> 6;
    float asv[FN], adv[FN];
    #pragma unroll
    for (int ni = 0; ni < FN; ++ni) {
      int d = ni * 16 + l16;
      asv[ni] = a_src[h * 64 + d];
      adv[ni] = a_dst[h * 64 + d];
    }
    #pragma unroll
    for (int mi = 0; mi < FM; ++mi) {
      #pragma unroll
      for (int r = 0; r < 4; ++r) {
        float ss = 0.f, sd = 0.f;
        #pragma unroll
        for (int ni = 0; ni < FN; ++ni) {
          float v = acc[mi][ni][r];
          ss = fmaf(v, asv[ni], ss);
          sd = fmaf(v, adv[ni], sd);
        }
        #pragma unroll
        for (int off = 1; off < 16; off <<= 1) {
          ss += __shfl_xor(ss, off, 64);
          sd += __shfl_xor(sd, off, 64);
        }
        int gm = bm + wm + mi * 16 + quad * 4 + r;
        if (l16 == 0 && gm < M) {
          s_src[gm * HS + h] = ss;
          s_dst[gm * HS + h] = sd;
        }
      }
    }
  }
}

// ---------------- CSR build over the NE real edges ----------------

// hist also records each edge's slot within its bucket (atomic return) so
// scatter needs no atomics.
__global__ __launch_bounds__(256)
void hist_kernel(const int* __restrict__ ei, int* __restrict__ cnt,
                 int* __restrict__ eslot) {
  int e = blockIdx.x * blockDim.x + threadIdx.x;
  if (e >= NE) return;
  eslot[e] = atomicAdd(&cnt[ei[NE + e]], 1);
}

__global__ __launch_bounds__(256)
void scan1_kernel(const int* __restrict__ in, int* __restrict__ out,
                  int* __restrict__ bsum, int n) {
  __shared__ int tmp[256];
  int t = threadIdx.x;
  int i = blockIdx.x * 256 + t;
  int v = (i < n) ? in[i] : 0;
  tmp[t] = v;
  __syncthreads();
  for (int off = 1; off < 256; off <<= 1) {
    int u = (t >= off) ? tmp[t - off] : 0;
    __syncthreads();
    tmp[t] += u;
    __syncthreads();
  }
  if (i <= n) out[i] = tmp[t] - v;
  if (t == 255) bsum[blockIdx.x] = tmp[255];
}

// scan2 merged: every block redundantly scans the (<=256) block sums in LDS.
__global__ __launch_bounds__(256)
void scan3_kernel(int* __restrict__ out, const int* __restrict__ bsum,
                  int n, int nb) {
  __shared__ int tmp[256];
  int t = threadIdx.x;
  int bv = (t < nb) ? bsum[t] : 0;
  tmp[t] = bv;
  __syncthreads();
  for (int off = 1; off < 256; off <<= 1) {
    int u = (t >= off) ? tmp[t - off] : 0;
    __syncthreads();
    tmp[t] += u;
    __syncthreads();
  }
  int add = tmp[blockIdx.x] - ((blockIdx.x < nb) ? bsum[blockIdx.x] : 0);
  int i = blockIdx.x * 256 + t;
  if (i > n) return;
  out[i] = out[i] + add;
}

// atomic-free scatter: pos = rowptr[d] + eslot[e]
__global__ __launch_bounds__(256)
void scatter_kernel(const int* __restrict__ ei, const int* __restrict__ rowptr,
                    const int* __restrict__ eslot, int* __restrict__ srcs) {
  int e = blockIdx.x * blockDim.x + threadIdx.x;
  if (e >= NE) return;
  int s = ei[e], d = ei[NE + e];
  srcs[rowptr[d] + eslot[e]] = s;
}

// ---------------- GAT1 aggregate (H=4): one wave per node, LDS-staged weights ----
// At the random-gather service ceiling (~6.7 TB/s request-level) -- round-0 config,
// with elu_neg replacing libm expm1f (-~200 VALU instrs/wave).
__global__ __launch_bounds__(256)
void gat_aggregate4(const int* __restrict__ rowptr, const int* __restrict__ srcs,
                    const float* __restrict__ ssrc, const float* __restrict__ sdst,
                    const __half* __restrict__ xh, const float* __restrict__ bias,
                    __half* __restrict__ out) {
  constexpr int H = 4, HD = 256;
  __shared__ float wbuf[4][64 * H];
  __shared__ int sbuf[4][64];
  const int wslot = threadIdx.x >> 6;
  const int wid = (blockIdx.x * blockDim.x + threadIdx.x) >> 6;
  const int lane = threadIdx.x & 63;
  if (wid >= NN) return;
  const int n = wid;
  const int start = rowptr[n];
  const int end = rowptr[n + 1];
  const int h = lane >> 4;

  float sdv[H];
  #pragma unroll
  for (int hh = 0; hh < H; ++hh) sdv[hh] = sdst[n * H + hh];

  float z;
  float acc[H];
  {
    float wself[H];
    #pragma unroll
    for (int hh = 0; hh < H; ++hh) {
      float e = ssrc[n * H + hh] + sdv[hh];
      e = e >= 0.f ? e : 0.2f * e;
      wself[hh] = __expf(e);
    }
    float ws = wself[h];
    z = ws;
    const __half* xr = xh + (size_t)n * HD + lane * H;
    float2 raw = *(const float2*)xr;
    __half2 p0 = *(__half2*)&raw.x;
    __half2 p1 = *(__half2*)&raw.y;
    float2 f0 = __half22float2(p0), f1 = __half22float2(p1);
    acc[0] = ws * f0.x; acc[1] = ws * f0.y; acc[2] = ws * f1.x; acc[3] = ws * f1.y;
  }

  for (int base = start; base < end; base += 64) {
    int cnt = end - base;
    if (cnt > 64) cnt = 64;
    if (lane < cnt) {
      int s = srcs[base + lane];
      sbuf[wslot][lane] = s;
      float4 t = *(const float4*)&ssrc[s * 4];
      float ev[H] = {t.x, t.y, t.z, t.w};
      #pragma unroll
      for (int hh = 0; hh < H; ++hh) {
        float e = ev[hh] + sdv[hh];
        e = e >= 0.f ? e : 0.2f * e;
        wbuf[wslot][lane * H + hh] = __expf(e);
      }
    }
    #pragma unroll 4
    for (int j = 0; j < cnt; ++j) {
      int s = sbuf[wslot][j];
      float w = wbuf[wslot][j * H + h];
      z += w;
      const __half* xr = xh + (size_t)s * HD + lane * H;
      float2 raw = *(const float2*)xr;
      __half2 p0 = *(__half2*)&raw.x;
      __half2 p1 = *(__half2*)&raw.y;
      float2 f0 = __half22float2(p0), f1 = __half22float2(p1);
      acc[0] = fmaf(w, f0.x, acc[0]); acc[1] = fmaf(w, f0.y, acc[1]);
      acc[2] = fmaf(w, f1.x, acc[2]); acc[3] = fmaf(w, f1.y, acc[3]);
    }
  }
  const float inv = 1.f / z;

  float v[4];
  #pragma unroll
  for (int i = 0; i < 4; ++i) {
    v[i] = acc[i] * inv + bias[lane * 4 + i];
    v[i] = v[i] > 0.f ? v[i] : elu_neg(v[i]);
  }
  union { __half2 h2[2]; float2 f2; } u;
  u.h2[0] = __floats2half2_rn(v[0], v[1]);
  u.h2[1] = __floats2half2_rn(v[2], v[3]);
  *(float2*)&out[(size_t)n * 256 + lane * 4] = u.f2;
}

// ---------------- GAT2 aggregate + fused GAT3 linear & scores ----------------
// Edge loop identical to r7; epilogue trimmed: elu_neg (no libm expm1f) and the
// GAT3 matvec uses 4 independent accumulators (64-deep fma chain -> 16-deep).
__global__ __launch_bounds__(256)
void gat_agg2_g3fused(const int* __restrict__ rowptr, const int* __restrict__ srcs,
                      const float* __restrict__ ssrc, const float* __restrict__ sdst,
                      const __half* __restrict__ xh,   // xh2 [NN][128]
                      const float* __restrict__ bias,  // g2b [64]
                      const __half* __restrict__ wtg3, // [64][64] transposed (out-major)
                      const float* __restrict__ a3s, const float* __restrict__ a3d,
                      __half* __restrict__ xh3,        // [NN][64] fp16
                      float* __restrict__ s3src, float* __restrict__ s3dst) {
  constexpr int H = 2, HD = 128, L8 = 32, NSUB = 2;
  __shared__ float wbuf[4][64 * H];
  __shared__ int sbuf[4][64];
  __shared__ __align__(16) __half a2h[4][64];
  const int wslot = threadIdx.x >> 6;
  const int wid = (blockIdx.x * blockDim.x + threadIdx.x) >> 6;
  const int lane = threadIdx.x & 63;
  if (wid >= NN) return;
  const int n = wid;
  const int start = rowptr[n];
  const int end = rowptr[n + 1];
  const int sub = lane / L8;        // which staged edge of the pack
  const int p = lane - sub * L8;    // 8 B slot within the row (cols p*4..p*4+3)
  const int hp = (p * 4) >> 6;      // head owning these columns

  float sdv[H];
  #pragma unroll
  for (int hh = 0; hh < H; ++hh) sdv[hh] = sdst[n * H + hh];

  float z = 0.f;
  float a0 = 0.f, a1 = 0.f, a2 = 0.f, a3 = 0.f;
  {
    float e = ssrc[n * H + hp] + sdv[hp];
    e = e >= 0.f ? e : 0.2f * e;
    float ws = __expf(e);
    if (sub == 0) {
      z = ws;
      float2 raw = *(const float2*)(xh + (size_t)n * HD + p * 4);
      __half2 q0 = *(__half2*)&raw.x, q1 = *(__half2*)&raw.y;
      float2 f0 = __half22float2(q0), f1 = __half22float2(q1);
      a0 = ws * f0.x; a1 = ws * f0.y; a2 = ws * f1.x; a3 = ws * f1.y;
    }
  }

  for (int base = start; base < end; base += 64) {
    int cnt = end - base;
    if (cnt > 64) cnt = 64;
    int cnt_pad = (cnt + NSUB - 1) & ~(NSUB - 1);
    if (lane < cnt) {
      int s = srcs[base + lane];
      sbuf[wslot][lane] = s;
      float2 t = *(const float2*)&ssrc[s * 2];
      float ev[H] = {t.x, t.y};
      #pragma unroll
      for (int hh = 0; hh < H; ++hh) {
        float e = ev[hh] + sdv[hh];
        e = e >= 0.f ? e : 0.2f * e;
        wbuf[wslot][lane * H + hh] = __expf(e);
      }
    } else if (lane < cnt_pad) {
      sbuf[wslot][lane] = n;        // safe row, zero weight
      #pragma unroll
      for (int hh = 0; hh < H; ++hh) wbuf[wslot][lane * H + hh] = 0.f;
    }
    #pragma unroll 4
    for (int j = 0; j < cnt; j += NSUB) {
      int e = j + sub;
      int s = sbuf[wslot][e];
      float w = wbuf[wslot][e * H + hp];
      z += w;
      float2 raw = *(const float2*)(xh + (size_t)s * HD + p * 4);
      __half2 q0 = *(__half2*)&raw.x, q1 = *(__half2*)&raw.y;
      float2 f0 = __half22float2(q0), f1 = __half22float2(q1);
      a0 = fmaf(w, f0.x, a0); a1 = fmaf(w, f0.y, a1);
      a2 = fmaf(w, f1.x, a2); a3 = fmaf(w, f1.y, a3);
    }
  }

  // combine sub partials (sub axis = lane^32)
  {
    z += __shfl_xor(z, 32, 64);
    a0 += __shfl_xor(a0, 32, 64);
    a1 += __shfl_xor(a1, 32, 64);
    a2 += __shfl_xor(a2, 32, 64);
    a3 += __shfl_xor(a3, 32, 64);
  }
  const float inv = 1.f / z;

  // mean over heads: lane p (head0 dims) pairs with lane p^16 (head1 same dims)
  float v0 = a0 * inv, v1 = a1 * inv, v2 = a2 * inv, v3 = a3 * inv;
  float o0 = __shfl_xor(v0, 16, 64);
  float o1 = __shfl_xor(v1, 16, 64);
  float o2 = __shfl_xor(v2, 16, 64);
  float o3 = __shfl_xor(v3, 16, 64);
  if (lane < 16) {
    float m0 = (v0 + o0) * 0.5f + bias[lane * 4 + 0];
    float m1 = (v1 + o1) * 0.5f + bias[lane * 4 + 1];
    float m2 = (v2 + o2) * 0.5f + bias[lane * 4 + 2];
    float m3 = (v3 + o3) * 0.5f + bias[lane * 4 + 3];
    m0 = m0 > 0.f ? m0 : elu_neg(m0);
    m1 = m1 > 0.f ? m1 : elu_neg(m1);
    m2 = m2 > 0.f ? m2 : elu_neg(m2);
    m3 = m3 > 0.f ? m3 : elu_neg(m3);
    *(__half2*)&a2h[wslot][lane * 4]     = __floats2half2_rn(m0, m1);
    *(__half2*)&a2h[wslot][lane * 4 + 2] = __floats2half2_rn(m2, m3);
  }
  __threadfence_block();   // order LDS write -> read (same wave, own wslot row)

  // ---- fused GAT3 linear: xh3[n][lane] = sum_k a2[k] * wtg3[lane][k] ----
  // 4 independent partial sums -> dependency chain 16 deep instead of 64.
  float c0 = 0.f, c1 = 0.f, c2 = 0.f, c3 = 0.f;
  {
    const float4* arow = (const float4*)&a2h[wslot][0];          // 8 x 16B (broadcast)
    const float4* wrow = (const float4*)(wtg3 + (size_t)lane * 64);
    #pragma unroll
    for (int i = 0; i < 8; i += 4) {
      float4 av0 = arow[i],     wv0 = wrow[i];
      float4 av1 = arow[i + 1], wv1 = wrow[i + 1];
      float4 av2 = arow[i + 2], wv2 = wrow[i + 2];
      float4 av3 = arow[i + 3], wv3 = wrow[i + 3];
      const __half2* ah0 = (const __half2*)&av0; const __half2* wh0 = (const __half2*)&wv0;
      const __half2* ah1 = (const __half2*)&av1; const __half2* wh1 = (const __half2*)&wv1;
      const __half2* ah2 = (const __half2*)&av2; const __half2* wh2 = (const __half2*)&wv2;
      const __half2* ah3 = (const __half2*)&av3; const __half2* wh3 = (const __half2*)&wv3;
      #pragma unroll
      for (int j = 0; j < 4; ++j) {
        float2 af0 = __half22float2(ah0[j]), wf0 = __half22float2(wh0[j]);
        float2 af1 = __half22float2(ah1[j]), wf1 = __half22float2(wh1[j]);
        float2 af2 = __half22float2(ah2[j]), wf2 = __half22float2(wh2[j]);
        float2 af3 = __half22float2(ah3[j]), wf3 = __half22float2(wh3[j]);
        c0 = fmaf(af0.x, wf0.x, c0); c0 = fmaf(af0.y, wf0.y, c0);
        c1 = fmaf(af1.x, wf1.x, c1); c1 = fmaf(af1.y, wf1.y, c1);
        c2 = fmaf(af2.x, wf2.x, c2); c2 = fmaf(af2.y, wf2.y, c2);
        c3 = fmaf(af3.x, wf3.x, c3); c3 = fmaf(af3.y, wf3.y, c3);
      }
    }
  }
  const float acc3 = (c0 + c1) + (c2 + c3);
  // GAT3 scores (1 head): reduce over the 64 dims
  float s3s = acc3 * a3s[lane];
  float s3d = acc3 * a3d[lane];
  #pragma unroll
  for (int off = 1; off < 64; off <<= 1) {
    s3s += __shfl_xor(s3s, off, 64);
    s3d += __shfl_xor(s3d, off, 64);
  }
  if (lane == 0) {
    s3src[n] = s3s;
    s3dst[n] = s3d;
  }
  xh3[(size_t)n * 64 + lane] = __float2half_rn(acc3);
}

// ---------------- GAT3 aggregate (H=1): staged multi-edge consume ----------------
__global__ __launch_bounds__(256)
void gat_aggregate3(const int* __restrict__ rowptr, const int* __restrict__ srcs,
                    const float* __restrict__ ssrc, const float* __restrict__ sdst,
                    const __half* __restrict__ xh,   // xh3 [NN][64]
                    const float* __restrict__ bias,  // g3b
                    float* __restrict__ out) {
  constexpr int HD = 64, L8 = 16, NSUB = 4;
  __shared__ float wbuf[4][64];
  __shared__ int sbuf[4][64];
  const int wslot = threadIdx.x >> 6;
  const int wid = (blockIdx.x * blockDim.x + threadIdx.x) >> 6;
  const int lane = threadIdx.x & 63;
  if (wid >= NN) return;
  const int n = wid;
  const int start = rowptr[n];
  const int end = rowptr[n + 1];
  const int sub = lane / L8;
  const int p = lane - sub * L8;

  const float sdv = sdst[n];

  float z = 0.f;
  float a0 = 0.f, a1 = 0.f, a2 = 0.f, a3 = 0.f;
  {
    float e = ssrc[n] + sdv;
    e = e >= 0.f ? e : 0.2f * e;
    float ws = __expf(e);
    if (sub == 0) {
      z = ws;
      float2 raw = *(const float2*)(xh + (size_t)n * HD + p * 4);
      __half2 q0 = *(__half2*)&raw.x, q1 = *(__half2*)&raw.y;
      float2 f0 = __half22float2(q0), f1 = __half22float2(q1);
      a0 = ws * f0.x; a1 = ws * f0.y; a2 = ws * f1.x; a3 = ws * f1.y;
    }
  }

  for (int base = start; base < end; base += 64) {
    int cnt = end - base;
    if (cnt > 64) cnt = 64;
    int cnt_pad = (cnt + NSUB - 1) & ~(NSUB - 1);
    if (lane < cnt) {
      int s = srcs[base + lane];
      sbuf[wslot][lane] = s;
      float e = ssrc[s] + sdv;
      e = e >= 0.f ? e : 0.2f * e;
      wbuf[wslot][lane] = __expf(e);
    } else if (lane < cnt_pad) {
      sbuf[wslot][lane] = n;
      wbuf[wslot][lane] = 0.f;
    }
    #pragma unroll 4
    for (int j = 0; j < cnt; j += NSUB) {
      int e = j + sub;
      int s = sbuf[wslot][e];
      float w = wbuf[wslot][e];
      z += w;
      float2 raw = *(const float2*)(xh + (size_t)s * HD + p * 4);
      __half2 q0 = *(__half2*)&raw.x, q1 = *(__half2*)&raw.y;
      float2 f0 = __half22float2(q0), f1 = __half22float2(q1);
      a0 = fmaf(w, f0.x, a0); a1 = fmaf(w, f0.y, a1);
      a2 = fmaf(w, f1.x, a2); a3 = fmaf(w, f1.y, a3);
    }
  }

  #pragma unroll
  for (int m = L8; m < 64; m <<= 1) {
    z += __shfl_xor(z, m, 64);
    a0 += __shfl_xor(a0, m, 64);
    a1 += __shfl_xor(a1, m, 64);
    a2 += __shfl_xor(a2, m, 64);
    a3 += __shfl_xor(a3, m, 64);
  }
  const float inv = 1.f / z;

  if (sub == 0) {
    float4 o = make_float4(a0 * inv + bias[p * 4 + 0],
                           a1 * inv + bias[p * 4 + 1],
                           a2 * inv + bias[p * 4 + 2],
                           a3 * inv + bias[p * 4 + 3]);
    *(float4*)&out[(size_t)n * 64 + p * 4] = o;
  }
}

// ---------------- orchestration ----------------

extern "C" void kernel_launch(void* const* d_in, const int* in_sizes, int n_in,
                              void* d_out, int out_size, void* d_ws, size_t ws_size,
                              hipStream_t stream) {
  const float* x    = (const float*)d_in[0];
  const int*   ei   = (const int*)d_in[1];
  const float* w1   = (const float*)d_in[2];
  const float* b1   = (const float*)d_in[3];
  const float* w2   = (const float*)d_in[4];
  const float* b2   = (const float*)d_in[5];
  const float* g1w  = (const float*)d_in[6];
  const float* g1as = (const float*)d_in[7];
  const float* g1ad = (const float*)d_in[8];
  const float* g1b  = (const float*)d_in[9];
  const float* g2w  = (const float*)d_in[10];
  const float* g2as = (const float*)d_in[11];
  const float* g2ad = (const float*)d_in[12];
  const float* g2b  = (const float*)d_in[13];
  const float* g3w  = (const float*)d_in[14];
  const float* g3as = (const float*)d_in[15];
  const float* g3ad = (const float*)d_in[16];
  const float* g3b  = (const float*)d_in[17];
  float* out = (float*)d_out;

  float* ws   = (float*)d_ws;
  float* bufA = ws;
  float* bufB = bufA + (size_t)NN * 256;
  float* bufC = bufB + (size_t)NN * 256;
  float* ssrc = bufC + (size_t)NN * 256;     // NN*4
  float* sdst = ssrc + (size_t)NN * 4;       // NN*4
  int* rowptr = (int*)(sdst + (size_t)NN * 4);  // NN+1
  int* cursor = rowptr + (NN + 1);              // NN
  int* bsum   = cursor + NN;                    // 256
  int* srcs   = bsum + 256;                     // NE
  __half* wt   = (__half*)(srcs + NE);          // 118784 halves
  __half* wt1  = wt;                            // 128x256
  __half* wt2  = wt + 32768;                    // 128x128
  __half* wtg1 = wt + 49152;                    // 256x128
  __half* wtg2 = wt + 81920;                    // 128x256
  __half* wtg3 = wt + 114688;                   // 64x64

  __half* xh1 = (__half*)bufC;   // NN*256
  __half* a1  = (__half*)bufA;   // NN*256
  __half* xh2 = (__half*)bufB;   // NN*128
  __half* xh3 = (__half*)bufA;   // NN*64  (a1 dead after gemm2)
  int* eslot  = (int*)bufB;      // NE ints (bufB dead during CSR build)
  float* s3src = ssrc + 2 * NN;  // upper half of GAT1 score region (dead)
  float* s3dst = sdst + 2 * NN;

  const int TB = 256;
  const int grid_m = ceil_div_h(NN, 64);        // 782
  const int egrid = ceil_div_h(NE, TB);
  const int sgrid = ceil_div_h(NN + 1, TB);
  const int wgrid = ceil_div_h(NN, 4);

  // ---- prep: weight convert + cursor zero ----
  prep_kernel<<<ceil_div_h(118784, TB), TB, 0, stream>>>(w1, w2, g1w, g2w, g3w, wt, cursor);

  // ---- CSR build ----
  hist_kernel<<<egrid, TB, 0, stream>>>(ei, cursor, eslot);
  scan1_kernel<<<sgrid, TB, 0, stream>>>(cursor, rowptr, bsum, NN);
  scan3_kernel<<<sgrid, TB, 0, stream>>>(rowptr, bsum, NN, sgrid);
  scatter_kernel<<<egrid, TB, 0, stream>>>(ei, rowptr, eslot, srcs);

  // ---- fused MLP + GAT1 linear: x -> h1 -> h2 -> xh1 (+scores) ----
  mlp_gat1_fused<<<grid_m, TB, 0, stream>>>(x, wt1, b1, wt2, b2, wtg1,
                                            g1as, g1ad, xh1, ssrc, sdst);
  gat_aggregate4<<<wgrid, TB, 0, stream>>>(rowptr, srcs, ssrc, sdst, xh1, g1b, a1);

  // ---- GAT2 linear: 256 -> 2x64 + scores ----
  mfma_gemm<64, 128, 2, 2, 0, 1, 0, 2><<<dim3(1, grid_m), TB, 0, stream>>>(
      a1, wtg2, nullptr, xh2, g2as, g2ad, ssrc, sdst, NN, 128, 256);

  // ---- GAT2 aggregate + fused GAT3 linear & scores ----
  gat_agg2_g3fused<<<wgrid, TB, 0, stream>>>(
      rowptr, srcs, ssrc, sdst, xh2, g2b, wtg3, g3as, g3ad, xh3, s3src, s3dst);

  // ---- GAT3 aggregate -> out ----
  gat_aggregate3<<<wgrid, TB, 0, stream>>>(
      rowptr, srcs, s3src, s3dst, xh3, g3b, out);
}